// Round 15
// baseline (296.258 us; speedup 1.0000x reference)
//
#include <hip/hip_runtime.h>
#include <hip/hip_bf16.h>

// GraphTransformerLayer on MI355X — round 15: ffn_ln reads W1/W2 direct from
// L2 (no LDS staging; LDS 80K->48K, runtime pads +2K so 80K was still 1
// block/CU) -> 3 blocks/CU; prep_w merged into hist. Rest = r14.
// N=50000, E=500000, D=128, H=8, DH=16.

#define D_ 128

typedef __attribute__((ext_vector_type(8))) short short8;
typedef __attribute__((ext_vector_type(4))) short short4v;
typedef __attribute__((ext_vector_type(4))) float f32x4;

__device__ __forceinline__ float b2f(ushort u) {
    union { uint u32; float f; } x; x.u32 = ((uint)u) << 16; return x.f;
}
__device__ __forceinline__ ushort f2b(float f) {
    union { __hip_bfloat16 h; ushort u; } v; v.h = __float2bfloat16(f); return v.u;
}

// ---------------------------------------------------------------------------
// bf16 MFMA GEMM (unchanged from r14): C[n x M] = A[n x K] @ W[M x K]^T
// AMODE 0: A bf16 via global_load_lds, 2-phase prefetch
//       1: A f32 reg-staged with convert (single buffer)
//       3: A f32 reg-staged + BN normalize in f32 THEN convert (K must be 128)
// EPI   0: bf16 store (+bias,+relu)
//       1: LN(resid + acc + bias) row-norm -> bf16 (M=128, grid.y=1)
//       2: y2 = acc + bias + BN1(y1res f32) -> f32 store + BN2 stats (M=128)
// ---------------------------------------------------------------------------
template<int AMODE, int EPI, bool RELU, bool RESF32>
__global__ __launch_bounds__(512) void gemm_bf16(
    const void* __restrict__ Aptr, const ushort* __restrict__ W,
    const float* __restrict__ bias, void* __restrict__ C,
    const float* __restrict__ bn_in, float* __restrict__ bn_out,
    const float* __restrict__ bng, const float* __restrict__ bnb,
    const void* __restrict__ resid, const float* __restrict__ y1res,
    const float* __restrict__ lng, const float* __restrict__ lnb,
    float invn, int n, int K, int M)
{
    __shared__ ushort Abuf[2][128 * 32];
    __shared__ ushort Bbuf[2][128 * 32];
    __shared__ float s_sh[128], t_sh[128];

    const int t    = threadIdx.x;
    const int lane = t & 63;
    const int w    = t >> 6;
    const int r0   = blockIdx.x * 128;
    const int c0   = blockIdx.y * 128;
    const int wr   = (w >> 1) * 32;
    const int wc   = (w & 1) * 64;
    const int rl   = lane & 15;
    const int kh   = lane >> 4;

    if (AMODE == 3 || EPI == 2) {
        if (t < 128) {
            float m   = bn_in[t] * invn;
            float var = bn_in[128 + t] * invn - m * m;
            float rs  = rsqrtf(var + 1e-5f);
            float s   = rs * bng[t];
            s_sh[t] = s;
            t_sh[t] = bnb[t] - m * s;
        }
        __syncthreads();
    }

    f32x4 acc[2][4] = {};
    const int nc = K >> 5;
    const int row = t >> 2, pos = t & 3;

    if (AMODE == 1 || AMODE == 3) {
        for (int c = 0; c < nc; ++c) {
            int kc = c * 32;
            const int ch = pos;
            int gr = r0 + row;
            short8 aval = {};
            if (gr < n) {
                const float* Af = (const float*)Aptr;
                float4 f0 = *reinterpret_cast<const float4*>(Af + (size_t)gr * K + kc + ch * 8);
                float4 f1 = *reinterpret_cast<const float4*>(Af + (size_t)gr * K + kc + ch * 8 + 4);
                float fv[8] = {f0.x, f0.y, f0.z, f0.w, f1.x, f1.y, f1.z, f1.w};
                #pragma unroll
                for (int q = 0; q < 8; ++q) {
                    float v = fv[q];
                    if (AMODE == 3) {
                        int cch = kc + ch * 8 + q;
                        v = fmaf(v, s_sh[cch], t_sh[cch]);
                    }
                    aval[q] = (short)f2b(v);
                }
            }
            short8 bval = *reinterpret_cast<const short8*>(W + (size_t)(c0 + row) * K + kc + ch * 8);
            __syncthreads();
            int sw = ch ^ ((row >> 1) & 3);
            *reinterpret_cast<short8*>(&Abuf[0][row * 32 + sw * 8]) = aval;
            *reinterpret_cast<short8*>(&Bbuf[0][row * 32 + sw * 8]) = bval;
            __syncthreads();
            short8 af[2], bfr[4];
            #pragma unroll
            for (int m = 0; m < 2; ++m) {
                int rr = wr + m * 16 + rl;
                af[m] = *reinterpret_cast<const short8*>(&Abuf[0][rr * 32 + (kh ^ ((rr >> 1) & 3)) * 8]);
            }
            #pragma unroll
            for (int nn = 0; nn < 4; ++nn) {
                int col = wc + nn * 16 + rl;
                bfr[nn] = *reinterpret_cast<const short8*>(&Bbuf[0][col * 32 + (kh ^ ((col >> 1) & 3)) * 8]);
            }
            #pragma unroll
            for (int m = 0; m < 2; ++m)
                #pragma unroll
                for (int nn = 0; nn < 4; ++nn)
                    acc[m][nn] = __builtin_amdgcn_mfma_f32_16x16x32_bf16(
                        bfr[nn], af[m], acc[m][nn], 0, 0, 0);
        }
    } else {
        const int ch = pos ^ ((row >> 1) & 3);
        const ushort* Abase = (const ushort*)Aptr + (size_t)(r0 + row) * K + ch * 8;
        const ushort* Bbase = W + (size_t)(c0 + row) * K + ch * 8;
        __builtin_amdgcn_global_load_lds(
            (const __attribute__((address_space(1))) void*)Abase,
            (__attribute__((address_space(3))) void*)&Abuf[0][t * 8], 16, 0, 0);
        __builtin_amdgcn_global_load_lds(
            (const __attribute__((address_space(1))) void*)Bbase,
            (__attribute__((address_space(3))) void*)&Bbuf[0][t * 8], 16, 0, 0);
        __syncthreads();
        for (int c = 0; c < nc; ++c) {
            if (c + 1 < nc) {
                int half = (c + 1) & 1;
                __builtin_amdgcn_global_load_lds(
                    (const __attribute__((address_space(1))) void*)(Abase + (c + 1) * 32),
                    (__attribute__((address_space(3))) void*)&Abuf[half][t * 8], 16, 0, 0);
                __builtin_amdgcn_global_load_lds(
                    (const __attribute__((address_space(1))) void*)(Bbase + (c + 1) * 32),
                    (__attribute__((address_space(3))) void*)&Bbuf[half][t * 8], 16, 0, 0);
            }
            const int cur = c & 1;
            short8 af[2], bfr[4];
            #pragma unroll
            for (int m = 0; m < 2; ++m) {
                int rr = wr + m * 16 + rl;
                af[m] = *reinterpret_cast<const short8*>(&Abuf[cur][rr * 32 + (kh ^ ((rr >> 1) & 3)) * 8]);
            }
            #pragma unroll
            for (int nn = 0; nn < 4; ++nn) {
                int col = wc + nn * 16 + rl;
                bfr[nn] = *reinterpret_cast<const short8*>(&Bbuf[cur][col * 32 + (kh ^ ((col >> 1) & 3)) * 8]);
            }
            #pragma unroll
            for (int m = 0; m < 2; ++m)
                #pragma unroll
                for (int nn = 0; nn < 4; ++nn)
                    acc[m][nn] = __builtin_amdgcn_mfma_f32_16x16x32_bf16(
                        bfr[nn], af[m], acc[m][nn], 0, 0, 0);
            __syncthreads();
        }
    }

    const int ch4 = kh * 4;

    if (EPI == 1) {
        __shared__ float lnS[128][2], lnS2[128][2];
        float4 bb[4];
        #pragma unroll
        for (int nn = 0; nn < 4; ++nn)
            bb[nn] = *reinterpret_cast<const float4*>(bias + wc + nn * 16 + ch4);
        #pragma unroll
        for (int m = 0; m < 2; ++m) {
            int r = r0 + wr + m * 16 + rl;
            float s = 0.f, s2 = 0.f;
            #pragma unroll
            for (int nn = 0; nn < 4; ++nn) {
                int c = wc + nn * 16 + ch4;
                float rv[4] = {0.f, 0.f, 0.f, 0.f};
                if (r < n) {
                    if (RESF32) {
                        float4 f = *reinterpret_cast<const float4*>((const float*)resid + (size_t)r * 128 + c);
                        rv[0] = f.x; rv[1] = f.y; rv[2] = f.z; rv[3] = f.w;
                    } else {
                        short4v f = *reinterpret_cast<const short4v*>((const ushort*)resid + (size_t)r * 128 + c);
                        rv[0] = b2f((ushort)f[0]); rv[1] = b2f((ushort)f[1]);
                        rv[2] = b2f((ushort)f[2]); rv[3] = b2f((ushort)f[3]);
                    }
                }
                float bj[4] = {bb[nn].x, bb[nn].y, bb[nn].z, bb[nn].w};
                #pragma unroll
                for (int j = 0; j < 4; ++j) {
                    float o = acc[m][nn][j] + bj[j] + rv[j];
                    acc[m][nn][j] = o;
                    s += o; s2 += o * o;
                }
            }
            s  += __shfl_xor(s, 16);  s  += __shfl_xor(s, 32);
            s2 += __shfl_xor(s2, 16); s2 += __shfl_xor(s2, 32);
            if (kh == 0) {
                lnS[wr + m * 16 + rl][w & 1]  = s;
                lnS2[wr + m * 16 + rl][w & 1] = s2;
            }
        }
        __syncthreads();
        #pragma unroll
        for (int m = 0; m < 2; ++m) {
            int rloc = wr + m * 16 + rl;
            int r = r0 + rloc;
            float S  = lnS[rloc][0] + lnS[rloc][1];
            float S2 = lnS2[rloc][0] + lnS2[rloc][1];
            float mean = S * (1.f / 128.f);
            float var  = S2 * (1.f / 128.f) - mean * mean;
            float rs   = rsqrtf(var + 1e-5f);
            if (r >= n) continue;
            #pragma unroll
            for (int nn = 0; nn < 4; ++nn) {
                int c = wc + nn * 16 + ch4;
                float4 gv = *reinterpret_cast<const float4*>(lng + c);
                float4 bv = *reinterpret_cast<const float4*>(lnb + c);
                float gj[4] = {gv.x, gv.y, gv.z, gv.w};
                float bj[4] = {bv.x, bv.y, bv.z, bv.w};
                short4v p;
                #pragma unroll
                for (int j = 0; j < 4; ++j)
                    p[j] = (short)f2b((acc[m][nn][j] - mean) * rs * gj[j] + bj[j]);
                *reinterpret_cast<short4v*>((ushort*)C + (size_t)r * 128 + c) = p;
            }
        }
        return;
    }

    if (EPI == 2) {
        __shared__ float csum[128], csum2[128];
        if (t < 128) { csum[t] = 0.f; csum2[t] = 0.f; }
        __syncthreads();
        float ps[4][4] = {};
        float ps2[4][4] = {};
        #pragma unroll
        for (int m = 0; m < 2; ++m) {
            int r = r0 + wr + m * 16 + rl;
            bool ok = r < n;
            #pragma unroll
            for (int nn = 0; nn < 4; ++nn) {
                int c = wc + nn * 16 + ch4;
                float4 bb = *reinterpret_cast<const float4*>(bias + c);
                float bj[4] = {bb.x, bb.y, bb.z, bb.w};
                float4 yv = make_float4(0.f, 0.f, 0.f, 0.f);
                if (ok) yv = *reinterpret_cast<const float4*>(y1res + (size_t)r * 128 + c);
                float yj[4] = {yv.x, yv.y, yv.z, yv.w};
                float oj[4];
                #pragma unroll
                for (int j = 0; j < 4; ++j) {
                    float o = 0.f;
                    if (ok) {
                        o = acc[m][nn][j] + bj[j]
                          + fmaf(yj[j], s_sh[c + j], t_sh[c + j]);
                    }
                    ps[nn][j] += o; ps2[nn][j] += o * o;
                    oj[j] = o;
                }
                if (ok) {
                    float4 o4 = make_float4(oj[0], oj[1], oj[2], oj[3]);
                    *reinterpret_cast<float4*>((float*)C + (size_t)r * 128 + c) = o4;
                }
            }
        }
        #pragma unroll
        for (int nn = 0; nn < 4; ++nn)
            #pragma unroll
            for (int j = 0; j < 4; ++j) {
                float a = ps[nn][j], b = ps2[nn][j];
                #pragma unroll
                for (int o2 = 1; o2 < 16; o2 <<= 1) {
                    a += __shfl_xor(a, o2);
                    b += __shfl_xor(b, o2);
                }
                if (rl == 0) {
                    int c = wc + nn * 16 + ch4 + j;
                    atomicAdd(&csum[c], a);
                    atomicAdd(&csum2[c], b);
                }
            }
        __syncthreads();
        if (t < 128) {
            atomicAdd(bn_out + t, csum[t]);
            atomicAdd(bn_out + 128 + t, csum2[t]);
        }
        return;
    }

    // EPI == 0
    #pragma unroll
    for (int m = 0; m < 2; ++m) {
        int r = r0 + wr + m * 16 + rl;
        if (r >= n) continue;
        #pragma unroll
        for (int nn = 0; nn < 4; ++nn) {
            int c = c0 + wc + nn * 16 + ch4;
            f32x4 vacc = acc[m][nn];
            float4 bb = make_float4(0.f, 0.f, 0.f, 0.f);
            if (bias) bb = *reinterpret_cast<const float4*>(bias + c);
            float o0 = vacc[0] + bb.x, o1 = vacc[1] + bb.y;
            float o2 = vacc[2] + bb.z, o3 = vacc[3] + bb.w;
            if (RELU) {
                o0 = fmaxf(o0, 0.f); o1 = fmaxf(o1, 0.f);
                o2 = fmaxf(o2, 0.f); o3 = fmaxf(o3, 0.f);
            }
            short4v p;
            p[0] = (short)f2b(o0); p[1] = (short)f2b(o1);
            p[2] = (short)f2b(o2); p[3] = (short)f2b(o3);
            *reinterpret_cast<short4v*>((ushort*)C + (size_t)r * M + c) = p;
        }
    }
}

// ---------------------------------------------------------------------------
// Fused FFN + LN2: out = LN(x + relu(x@W1^T+b1)@W2^T + b2), 128-row block.
// Weights read DIRECTLY from global (L2-resident, shared by all blocks);
// LDS = Xs 32K + FF1 16K = 48K -> 3 blocks/CU. FF chunk = 64, 8 chunks.
// 512 threads = 8 waves; per chunk: stage1 MFMA -> FF1 -> barrier -> stage2
// MFMA accumulate -> barrier.
// ---------------------------------------------------------------------------
__global__ __launch_bounds__(512) void ffn_ln_kernel(
    const ushort* __restrict__ X,   const ushort* __restrict__ W1g,  // 512x128
    const ushort* __restrict__ W2g,                                   // 128x512
    const float* __restrict__ b1v,  const float* __restrict__ b2v,
    const float* __restrict__ lng,  const float* __restrict__ lnb,
    ushort* __restrict__ out, int n)
{
    __shared__ ushort Xs[128 * 128];      // 32KB, 16 chunks/row, swz &7
    __shared__ ushort FF1[128 * 64];      // 16KB, 8 chunks/row, swz &7 (lnS alias)

    const int t    = threadIdx.x;
    const int lane = t & 63;
    const int w    = t >> 6;
    const int r0   = blockIdx.x * 128;
    const int rl   = lane & 15;
    const int kh   = lane >> 4;
    const int wr   = (w >> 1) * 32;       // row group (both stages)
    const int wc1  = (w & 1) * 32;        // stage1 col group (of 64-chunk)
    const int wc2  = (w & 1) * 64;        // stage2 col group (of 128)

    // ---- prologue: X tile ----
    #pragma unroll
    for (int i = 0; i < 4; ++i) {
        int s = t + i * 512;
        int row = s >> 4, pos = s & 15;
        int srcch = pos ^ ((row >> 1) & 7);
        if (r0 + row < n)
            __builtin_amdgcn_global_load_lds(
                (const __attribute__((address_space(1))) void*)(X + (size_t)(r0 + row) * 128 + srcch * 8),
                (__attribute__((address_space(3))) void*)&Xs[s * 8], 16, 0, 0);
    }
    __syncthreads();

    f32x4 acc2[2][4] = {};

    for (int c = 0; c < 8; ++c) {
        // ---- stage 1: ff1 chunk = relu(x @ W1c^T + b1c), 128x64 (wave 32x32)
        f32x4 acc1[2][2] = {};
        #pragma unroll
        for (int ks = 0; ks < 4; ++ks) {
            int chn = ks * 4 + kh;
            short8 af[2], bf[2];
            #pragma unroll
            for (int m = 0; m < 2; ++m) {
                int row = wr + m * 16 + rl;
                af[m] = *reinterpret_cast<const short8*>(&Xs[row * 128 + (chn ^ ((row >> 1) & 7)) * 8]);
            }
            #pragma unroll
            for (int nn = 0; nn < 2; ++nn) {
                int colL = wc1 + nn * 16 + rl;
                bf[nn] = *reinterpret_cast<const short8*>(
                    W1g + (size_t)(c * 64 + colL) * 128 + chn * 8);
            }
            #pragma unroll
            for (int m = 0; m < 2; ++m)
                #pragma unroll
                for (int nn = 0; nn < 2; ++nn)
                    acc1[m][nn] = __builtin_amdgcn_mfma_f32_16x16x32_bf16(
                        bf[nn], af[m], acc1[m][nn], 0, 0, 0);
        }
        #pragma unroll
        for (int m = 0; m < 2; ++m) {
            int row = wr + m * 16 + rl;
            #pragma unroll
            for (int nn = 0; nn < 2; ++nn) {
                int colL = wc1 + nn * 16 + kh * 4;
                float4 bb = *reinterpret_cast<const float4*>(b1v + c * 64 + colL);
                short4v p;
                p[0] = (short)f2b(fmaxf(acc1[m][nn][0] + bb.x, 0.f));
                p[1] = (short)f2b(fmaxf(acc1[m][nn][1] + bb.y, 0.f));
                p[2] = (short)f2b(fmaxf(acc1[m][nn][2] + bb.z, 0.f));
                p[3] = (short)f2b(fmaxf(acc1[m][nn][3] + bb.w, 0.f));
                int chn = colL >> 3, half = (colL >> 2) & 1;
                *reinterpret_cast<short4v*>(
                    &FF1[row * 64 + (chn ^ ((row >> 1) & 7)) * 8 + half * 4]) = p;
            }
        }
        __syncthreads();   // FF1 visible to all waves

        // ---- stage 2: acc2 += ff1c @ W2c^T, 128x128 (wave 32x64), K=64
        #pragma unroll
        for (int ks = 0; ks < 2; ++ks) {
            int chn = ks * 4 + kh;
            short8 af[2], bf[4];
            #pragma unroll
            for (int m = 0; m < 2; ++m) {
                int row = wr + m * 16 + rl;
                af[m] = *reinterpret_cast<const short8*>(&FF1[row * 64 + (chn ^ ((row >> 1) & 7)) * 8]);
            }
            #pragma unroll
            for (int nn = 0; nn < 4; ++nn) {
                int col = wc2 + nn * 16 + rl;
                bf[nn] = *reinterpret_cast<const short8*>(
                    W2g + (size_t)col * 512 + c * 64 + chn * 8);
            }
            #pragma unroll
            for (int m = 0; m < 2; ++m)
                #pragma unroll
                for (int nn = 0; nn < 4; ++nn)
                    acc2[m][nn] = __builtin_amdgcn_mfma_f32_16x16x32_bf16(
                        bf[nn], af[m], acc2[m][nn], 0, 0, 0);
        }
        __syncthreads();   // stage2 FF1 reads done -> safe to overwrite next chunk
    }

    // ---- epilogue: LN(x + acc2 + b2) -> out (residual x from LDS) ----
    float* lnSf  = (float*)FF1;          // alias (dead; fenced by last barrier)
    float* lnS2f = lnSf + 256;
    const int ch4 = kh * 4;
    #pragma unroll
    for (int m = 0; m < 2; ++m) {
        int rloc = wr + m * 16 + rl;
        float s = 0.f, s2 = 0.f;
        #pragma unroll
        for (int nn = 0; nn < 4; ++nn) {
            int col = wc2 + nn * 16 + ch4;
            int chn = col >> 3;
            short4v xv = *reinterpret_cast<const short4v*>(
                &Xs[rloc * 128 + (chn ^ ((rloc >> 1) & 7)) * 8 + ((col >> 2) & 1) * 4]);
            float4 bb = *reinterpret_cast<const float4*>(b2v + col);
            float bj[4] = {bb.x, bb.y, bb.z, bb.w};
            #pragma unroll
            for (int j = 0; j < 4; ++j) {
                float o = acc2[m][nn][j] + bj[j] + b2f((ushort)xv[j]);
                acc2[m][nn][j] = o;
                s += o; s2 += o * o;
            }
        }
        s  += __shfl_xor(s, 16);  s  += __shfl_xor(s, 32);
        s2 += __shfl_xor(s2, 16); s2 += __shfl_xor(s2, 32);
        if (kh == 0) {
            lnSf[rloc * 2 + (w & 1)]  = s;
            lnS2f[rloc * 2 + (w & 1)] = s2;
        }
    }
    __syncthreads();
    #pragma unroll
    for (int m = 0; m < 2; ++m) {
        int rloc = wr + m * 16 + rl;
        int r = r0 + rloc;
        float S  = lnSf[rloc * 2 + 0] + lnSf[rloc * 2 + 1];
        float S2 = lnS2f[rloc * 2 + 0] + lnS2f[rloc * 2 + 1];
        float mean = S * (1.f / 128.f);
        float var  = S2 * (1.f / 128.f) - mean * mean;
        float rs   = rsqrtf(var + 1e-5f);
        if (r >= n) continue;
        #pragma unroll
        for (int nn = 0; nn < 4; ++nn) {
            int col = wc2 + nn * 16 + ch4;
            float4 gv = *reinterpret_cast<const float4*>(lng + col);
            float4 bv = *reinterpret_cast<const float4*>(lnb + col);
            float gj[4] = {gv.x, gv.y, gv.z, gv.w};
            float bj[4] = {bv.x, bv.y, bv.z, bv.w};
            short4v p;
            #pragma unroll
            for (int j = 0; j < 4; ++j)
                p[j] = (short)f2b((acc2[m][nn][j] - mean) * rs * gj[j] + bj[j]);
            *reinterpret_cast<short4v*>(out + (size_t)r * 128 + col) = p;
        }
    }
}

// ---------------------------------------------------------------------------
__global__ __launch_bounds__(256) void zero_kernel(int4* __restrict__ p, int n4)
{
    int i = blockIdx.x * blockDim.x + threadIdx.x;
    int stride = gridDim.x * blockDim.x;
    int4 z = make_int4(0, 0, 0, 0);
    for (; i < n4; i += stride) p[i] = z;
}

// ---------------------------------------------------------------------------
// Merged histogram + weight prep: blocks [0,Eb) hist dst; blocks [Eb,Eb+304)
// convert weights / fuse Wf.
// ---------------------------------------------------------------------------
struct WPtrs { const float* p[7]; };

__global__ __launch_bounds__(256) void hist_prep_kernel(
    const int* __restrict__ dst, int* __restrict__ cnt, int E_, int Eb,
    const float* __restrict__ Win, const float* __restrict__ bin_,
    const float* __restrict__ Wout, const float* __restrict__ bout,
    WPtrs wp, ushort* __restrict__ wbf, float* __restrict__ bfused)
{
    int blk = blockIdx.x;
    if (blk < Eb) {
        int e = blk * 256 + threadIdx.x;
        if (e < E_) atomicAdd(cnt + dst[e], 1);
        return;
    }
    int b = blk - Eb;
    if (b < 64) {
        int idx = b * 256 + threadIdx.x;
        int i = idx >> 7, c = idx & 127;
        const float* WinV = Win + 256 * 128;
        float s = 0.f;
        for (int j = 0; j < 128; ++j)
            s = fmaf(Wout[i * 128 + j], WinV[j * 128 + c], s);
        wbf[245760 + idx] = f2b(s);
        if (c == 0) {
            float tb = bout[i];
            for (int j = 0; j < 128; ++j)
                tb = fmaf(Wout[i * 128 + j], bin_[256 + j], tb);
            bfused[i] = tb;
        }
    } else {
        const int off[8] = {0, 65536, 131072, 147456, 163840, 180224, 212992, 245760};
        int e0 = ((b - 64) * 256 + threadIdx.x) * 4;
        if (e0 >= 245760) return;
        int s = 0;
        #pragma unroll
        for (int j = 1; j < 7; ++j) if (e0 >= off[j]) s = j;
        float4 f = *reinterpret_cast<const float4*>(wp.p[s] + (e0 - off[s]));
        short4v o;
        o[0] = (short)f2b(f.x); o[1] = (short)f2b(f.y);
        o[2] = (short)f2b(f.z); o[3] = (short)f2b(f.w);
        *reinterpret_cast<short4v*>(wbf + e0) = o;
    }
}

__global__ __launch_bounds__(256) void scan_block_kernel(
    int* __restrict__ data, int* __restrict__ bsum, int n)
{
    __shared__ int tmp[256];
    int i = blockIdx.x * 256 + threadIdx.x;
    int v = (i < n) ? data[i] : 0;
    tmp[threadIdx.x] = v;
    __syncthreads();
    #pragma unroll
    for (int o = 1; o < 256; o <<= 1) {
        int y = (threadIdx.x >= o) ? tmp[threadIdx.x - o] : 0;
        __syncthreads();
        tmp[threadIdx.x] += y;
        __syncthreads();
    }
    if (i < n) data[i] = tmp[threadIdx.x] - v;
    if (threadIdx.x == 255) bsum[blockIdx.x] = tmp[255];
}

__global__ __launch_bounds__(256) void add_off_kernel(
    int* __restrict__ data, const int* __restrict__ bsum, int n, int nb)
{
    __shared__ int red[4];
    int b = blockIdx.x;
    int v = (threadIdx.x < b && threadIdx.x < nb) ? bsum[threadIdx.x] : 0;
    #pragma unroll
    for (int o = 1; o < 64; o <<= 1) v += __shfl_xor(v, o);
    if ((threadIdx.x & 63) == 0) red[threadIdx.x >> 6] = v;
    __syncthreads();
    int off = red[0] + red[1] + red[2] + red[3];
    int i = b * 256 + threadIdx.x;
    if (i < n) data[i] += off;
}

__global__ void scatter_kernel(const int* __restrict__ src, const int* __restrict__ dst,
                               int* __restrict__ rowptr, int* __restrict__ csr_src, int E_)
{
    int e = blockIdx.x * blockDim.x + threadIdx.x;
    if (e >= E_) return;
    int pos = atomicAdd(rowptr + dst[e], 1);
    csr_src[pos] = src[e];
}

// ---------------------------------------------------------------------------
// Gather attention: 32 lanes/node = 4 edge-slots x 8 heads (proven shape).
// Writes y1 = hsub + wV/z as FLOAT32.
// ---------------------------------------------------------------------------
__global__ __launch_bounds__(256) void attn_agg_kernel(
    const int* __restrict__ rowptr, const int* __restrict__ csr_src,
    const ushort* __restrict__ QKV, const ushort* __restrict__ hsub,
    float* __restrict__ out, int n)
{
    int node  = (blockIdx.x * blockDim.x + threadIdx.x) >> 5;
    int lane5 = threadIdx.x & 31;
    int slot  = lane5 >> 3;   // 0..3
    int hd    = lane5 & 7;    // head; channels [16*hd, 16*hd+16)
    bool valid = node < n;
    int nd = valid ? node : 0;
    int start = (valid && nd) ? rowptr[nd - 1] : 0;
    int end   = valid ? rowptr[nd] : 0;

    const ushort* qp = QKV + (size_t)nd * 384 + hd * 16;
    short8 q0 = *reinterpret_cast<const short8*>(qp);
    short8 q1 = *reinterpret_cast<const short8*>(qp + 8);
    float q[16];
    #pragma unroll
    for (int i = 0; i < 8; ++i) { q[i] = b2f((ushort)q0[i]); q[8 + i] = b2f((ushort)q1[i]); }

    float acc[16] = {};
    float zh = 0.f;
    for (int j = start; j < end; j += 4) {
        int idx = j + slot;
        if (idx < end) {
            int s = csr_src[idx];
            const ushort* kp = QKV + (size_t)s * 384 + 128 + hd * 16;
            short8 k0 = *reinterpret_cast<const short8*>(kp);
            short8 k1 = *reinterpret_cast<const short8*>(kp + 8);
            float p = 0.f;
            #pragma unroll
            for (int i = 0; i < 8; ++i) {
                p = fmaf(b2f((ushort)k0[i]), q[i], p);
                p = fmaf(b2f((ushort)k1[i]), q[8 + i], p);
            }
            float sc = __expf(fminf(fmaxf(p * 0.25f, -5.f), 5.f));
            short8 v0 = *reinterpret_cast<const short8*>(kp + 128);
            short8 v1 = *reinterpret_cast<const short8*>(kp + 136);
            #pragma unroll
            for (int i = 0; i < 8; ++i) {
                acc[i]     = fmaf(sc, b2f((ushort)v0[i]), acc[i]);
                acc[8 + i] = fmaf(sc, b2f((ushort)v1[i]), acc[8 + i]);
            }
            zh += sc;
        }
    }
    #pragma unroll
    for (int i = 0; i < 16; ++i) {
        acc[i] += __shfl_xor(acc[i], 8);
        acc[i] += __shfl_xor(acc[i], 16);
    }
    zh += __shfl_xor(zh, 8);
    zh += __shfl_xor(zh, 16);

    if (slot == 0 && valid) {
        const ushort* hp = hsub + (size_t)nd * D_ + hd * 16;
        short8 h0 = *reinterpret_cast<const short8*>(hp);
        short8 h1 = *reinterpret_cast<const short8*>(hp + 8);
        float inv = 1.f / zh;
        float* op = out + (size_t)nd * D_ + hd * 16;
        float4 o;
        o.x = b2f((ushort)h0[0]) + acc[0] * inv;
        o.y = b2f((ushort)h0[1]) + acc[1] * inv;
        o.z = b2f((ushort)h0[2]) + acc[2] * inv;
        o.w = b2f((ushort)h0[3]) + acc[3] * inv;
        reinterpret_cast<float4*>(op)[0] = o;
        o.x = b2f((ushort)h0[4]) + acc[4] * inv;
        o.y = b2f((ushort)h0[5]) + acc[5] * inv;
        o.z = b2f((ushort)h0[6]) + acc[6] * inv;
        o.w = b2f((ushort)h0[7]) + acc[7] * inv;
        reinterpret_cast<float4*>(op)[1] = o;
        o.x = b2f((ushort)h1[0]) + acc[8]  * inv;
        o.y = b2f((ushort)h1[1]) + acc[9]  * inv;
        o.z = b2f((ushort)h1[2]) + acc[10] * inv;
        o.w = b2f((ushort)h1[3]) + acc[11] * inv;
        reinterpret_cast<float4*>(op)[2] = o;
        o.x = b2f((ushort)h1[4]) + acc[12] * inv;
        o.y = b2f((ushort)h1[5]) + acc[13] * inv;
        o.z = b2f((ushort)h1[6]) + acc[14] * inv;
        o.w = b2f((ushort)h1[7]) + acc[15] * inv;
        reinterpret_cast<float4*>(op)[3] = o;
    }
}

// ---------------------------------------------------------------------------
// BN stats over FLOAT input: sums[c], sums[128+c].
// ---------------------------------------------------------------------------
__global__ __launch_bounds__(256) void bn_stats_kernel(
    const float* __restrict__ x, float* __restrict__ sums, int n)
{
    int c    = threadIdx.x & 127;
    int half = threadIdx.x >> 7;
    float s = 0.f, s2 = 0.f;
    for (int r = blockIdx.x * 2 + half; r < n; r += gridDim.x * 2) {
        float v = x[(size_t)r * D_ + c];
        s += v; s2 += v * v;
    }
    __shared__ float ls[256], ls2[256];
    ls[threadIdx.x] = s; ls2[threadIdx.x] = s2;
    __syncthreads();
    if (half == 0) {
        s  += ls[threadIdx.x + 128];
        s2 += ls2[threadIdx.x + 128];
        atomicAdd(sums + c, s);
        atomicAdd(sums + 128 + c, s2);
    }
}

// final BN: FLOAT in -> f32 out, 4 elems/thread
__global__ void bn_norm_kernel(const float* __restrict__ x,
                               const float* __restrict__ stats,
                               const float* __restrict__ g, const float* __restrict__ b,
                               float* __restrict__ out, float invn, int total4)
{
    int i = blockIdx.x * blockDim.x + threadIdx.x;
    if (i >= total4) return;
    int cb = (i << 2) & 127;
    float4 v = reinterpret_cast<const float4*>(x)[i];
    float vj[4] = {v.x, v.y, v.z, v.w};
    float r[4];
    #pragma unroll
    for (int q = 0; q < 4; ++q) {
        int c = cb + q;
        float m   = stats[c] * invn;
        float var = stats[128 + c] * invn - m * m;
        float rs  = rsqrtf(var + 1e-5f);
        r[q] = (vj[q] - m) * rs * g[c] + b[c];
    }
    float4 o; o.x = r[0]; o.y = r[1]; o.z = r[2]; o.w = r[3];
    reinterpret_cast<float4*>(out)[i] = o;
}

// ---------------------------------------------------------------------------
extern "C" void kernel_launch(void* const* d_in, const int* in_sizes, int n_in,
                              void* d_out, int out_size, void* d_ws, size_t ws_size,
                              hipStream_t stream)
{
    const float* h    = (const float*)d_in[0];
    const int*   src  = (const int*)d_in[1];
    const int*   dst  = (const int*)d_in[2];
    const float* Win  = (const float*)d_in[3];
    const float* bin_ = (const float*)d_in[4];
    const float* Wout = (const float*)d_in[5];
    const float* bout = (const float*)d_in[6];
    const float* Wte1 = (const float*)d_in[7];
    const float* bte1 = (const float*)d_in[8];
    const float* Wte2 = (const float*)d_in[9];
    const float* bte2 = (const float*)d_in[10];
    const float* ln1g = (const float*)d_in[11];
    const float* ln1b = (const float*)d_in[12];
    const float* ln2g = (const float*)d_in[13];
    const float* ln2b = (const float*)d_in[14];
    const float* WQ   = (const float*)d_in[15];
    const float* WK   = (const float*)d_in[16];
    const float* WV   = (const float*)d_in[17];
    const float* W1   = (const float*)d_in[18];
    const float* b1   = (const float*)d_in[19];
    const float* W2   = (const float*)d_in[20];
    const float* b2   = (const float*)d_in[21];
    const float* bn1g = (const float*)d_in[22];
    const float* bn1b = (const float*)d_in[23];
    const float* bn2g = (const float*)d_in[24];
    const float* bn2b = (const float*)d_in[25];

    const int N_ = in_sizes[0] / D_;
    const int E_ = in_sizes[1];
    const size_t S2 = (size_t)N_ * D_ / 2;   // float units of one NxD bf16 buffer

    float* ws = (float*)d_ws;
    size_t off_tail = 10 * S2;
    size_t need = (off_tail + 131072 + 128 + 512) * sizeof(float)
                + (size_t)(N_ + E_ + 256) * sizeof(int) + 4096;
    if (ws_size < need) return;

    ushort* bufA   = (ushort*)ws;                 // x (bf16)
    ushort* bufC   = (ushort*)(ws + S2);          // hsub (bf16)
    ushort* bufD   = (ushort*)(ws + 2 * S2);      // QKV / f1 (bf16)
    float*  y1f    = ws + 6 * S2;
    float*  y2f    = ws + 8 * S2;
    ushort* wbf    = (ushort*)(ws + off_tail);
    float*  bfused = ws + off_tail + 131072;
    float*  stats  = bfused + 128;
    int* rowptr  = (int*)(stats + 512);
    int* csr_src = rowptr + N_;
    int* bsum    = csr_src + E_;

    const ushort* Wte1_bf = wbf;
    const ushort* Wte2_bf = wbf + 65536;
    const ushort* WQKV_bf = wbf + 131072;
    const ushort* W1_bf   = wbf + 180224;
    const ushort* W2_bf   = wbf + 212992;
    ushort*       Wf_bf   = wbf + 245760;

    dim3 blk(256);
    dim3 blk512(512);
    const int rowBlocks = (N_ + 127) / 128;
    const int totElems  = N_ * D_;
    const dim3 gNode((N_ + 7) / 8);               // 8 nodes/block (32 lanes/node)
    const int nb = (N_ + 255) / 256;
    const int Eb = (E_ + 255) / 256;
    const float invn = 1.f / (float)N_;

    {
        int n4 = (512 + N_) / 4;
        int zblocks = (n4 + 255) / 256;
        if (zblocks > 128) zblocks = 128;
        zero_kernel<<<dim3(zblocks), blk, 0, stream>>>((int4*)stats, n4);
    }

    // --- CSR build + weight prep (hist and prep merged) ---
    WPtrs wp;
    wp.p[0] = Wte1; wp.p[1] = Wte2; wp.p[2] = WQ; wp.p[3] = WK; wp.p[4] = WV;
    wp.p[5] = W1;   wp.p[6] = W2;
    hist_prep_kernel<<<dim3(Eb + 304), blk, 0, stream>>>(
        dst, rowptr, E_, Eb, Win, bin_, Wout, bout, wp, wbf, bfused);
    scan_block_kernel<<<dim3(nb), blk, 0, stream>>>(rowptr, bsum, N_);
    add_off_kernel<<<dim3(nb), blk, 0, stream>>>(rowptr, bsum, N_, nb);
    scatter_kernel<<<dim3(Eb), blk, 0, stream>>>(src, dst, rowptr, csr_src, E_);

    // --- per-node TransformerEncoder ---
    gemm_bf16<1, 1, false, true><<<dim3(rowBlocks, 1), blk512, 0, stream>>>(
        h, Wf_bf, bfused, bufA, nullptr, nullptr, nullptr, nullptr,
        h, nullptr, ln1g, ln1b, 0.f, N_, 128, 128);
    ffn_ln_kernel<<<dim3(rowBlocks), blk512, 0, stream>>>(
        bufA, Wte1_bf, Wte2_bf, bte1, bte2, ln2g, ln2b, bufC, N_);

    // --- graph multi-head attention ---
    gemm_bf16<0, 0, false, false><<<dim3(rowBlocks, 3), blk512, 0, stream>>>(
        bufC, WQKV_bf, nullptr, bufD, nullptr, nullptr, nullptr, nullptr,
        nullptr, nullptr, nullptr, nullptr, 0.f, N_, 128, 384);
    attn_agg_kernel<<<gNode, blk, 0, stream>>>(
        rowptr, csr_src, bufD, bufC, y1f, N_);                           // y1 (f32)

    // --- BN1 stats ---
    bn_stats_kernel<<<dim3(512), blk, 0, stream>>>(y1f, stats, N_);

    // --- FFN + BN2 ---
    gemm_bf16<3, 0, true, false><<<dim3(rowBlocks, 2), blk512, 0, stream>>>(
        y1f, W1_bf, b1, bufD, stats, nullptr, bn1g, bn1b,
        nullptr, nullptr, nullptr, nullptr, invn, N_, 128, 256);
    gemm_bf16<0, 2, false, false><<<dim3(rowBlocks, 1), blk512, 0, stream>>>(
        bufD, W2_bf, b2, y2f, stats, stats + 256, bn1g, bn1b,
        nullptr, y1f, nullptr, nullptr, invn, N_, 256, 128);
    bn_norm_kernel<<<dim3((totElems / 4 + 255) / 256), blk, 0, stream>>>(
        y2f, stats + 256, bn2g, bn2b, (float*)d_out, invn, totElems / 4);
}

// Round 16
// 256.424 us; speedup vs baseline: 1.1553x; 1.1553x over previous
//
#include <hip/hip_runtime.h>
#include <hip/hip_bf16.h>

// GraphTransformerLayer on MI355X — round 16: ffn_ln with W1/W2 time-sharing
// one 16KB LDS buffer (64KB total -> 2 blocks/CU; r14's 80KB was padded to
// 82KB -> 1 block/CU; r15's direct-L2 reads collapsed MfmaUtil to 6.6%).
// Numerics identical to r14. N=50000, E=500000, D=128, H=8, DH=16.

#define D_ 128

typedef __attribute__((ext_vector_type(8))) short short8;
typedef __attribute__((ext_vector_type(4))) short short4v;
typedef __attribute__((ext_vector_type(4))) float f32x4;

__device__ __forceinline__ float b2f(ushort u) {
    union { uint u32; float f; } x; x.u32 = ((uint)u) << 16; return x.f;
}
__device__ __forceinline__ ushort f2b(float f) {
    union { __hip_bfloat16 h; ushort u; } v; v.h = __float2bfloat16(f); return v.u;
}

// ---------------------------------------------------------------------------
// bf16 MFMA GEMM (unchanged from r14): C[n x M] = A[n x K] @ W[M x K]^T
// AMODE 0: A bf16 via global_load_lds, 2-phase prefetch
//       1: A f32 reg-staged with convert (single buffer)
//       3: A f32 reg-staged + BN normalize in f32 THEN convert (K must be 128)
// EPI   0: bf16 store (+bias,+relu)
//       1: LN(resid + acc + bias) row-norm -> bf16 (M=128, grid.y=1)
//       2: y2 = acc + bias + BN1(y1res f32) -> f32 store + BN2 stats (M=128)
// ---------------------------------------------------------------------------
template<int AMODE, int EPI, bool RELU, bool RESF32>
__global__ __launch_bounds__(512) void gemm_bf16(
    const void* __restrict__ Aptr, const ushort* __restrict__ W,
    const float* __restrict__ bias, void* __restrict__ C,
    const float* __restrict__ bn_in, float* __restrict__ bn_out,
    const float* __restrict__ bng, const float* __restrict__ bnb,
    const void* __restrict__ resid, const float* __restrict__ y1res,
    const float* __restrict__ lng, const float* __restrict__ lnb,
    float invn, int n, int K, int M)
{
    __shared__ ushort Abuf[2][128 * 32];
    __shared__ ushort Bbuf[2][128 * 32];
    __shared__ float s_sh[128], t_sh[128];

    const int t    = threadIdx.x;
    const int lane = t & 63;
    const int w    = t >> 6;
    const int r0   = blockIdx.x * 128;
    const int c0   = blockIdx.y * 128;
    const int wr   = (w >> 1) * 32;
    const int wc   = (w & 1) * 64;
    const int rl   = lane & 15;
    const int kh   = lane >> 4;

    if (AMODE == 3 || EPI == 2) {
        if (t < 128) {
            float m   = bn_in[t] * invn;
            float var = bn_in[128 + t] * invn - m * m;
            float rs  = rsqrtf(var + 1e-5f);
            float s   = rs * bng[t];
            s_sh[t] = s;
            t_sh[t] = bnb[t] - m * s;
        }
        __syncthreads();
    }

    f32x4 acc[2][4] = {};
    const int nc = K >> 5;
    const int row = t >> 2, pos = t & 3;

    if (AMODE == 1 || AMODE == 3) {
        for (int c = 0; c < nc; ++c) {
            int kc = c * 32;
            const int ch = pos;
            int gr = r0 + row;
            short8 aval = {};
            if (gr < n) {
                const float* Af = (const float*)Aptr;
                float4 f0 = *reinterpret_cast<const float4*>(Af + (size_t)gr * K + kc + ch * 8);
                float4 f1 = *reinterpret_cast<const float4*>(Af + (size_t)gr * K + kc + ch * 8 + 4);
                float fv[8] = {f0.x, f0.y, f0.z, f0.w, f1.x, f1.y, f1.z, f1.w};
                #pragma unroll
                for (int q = 0; q < 8; ++q) {
                    float v = fv[q];
                    if (AMODE == 3) {
                        int cch = kc + ch * 8 + q;
                        v = fmaf(v, s_sh[cch], t_sh[cch]);
                    }
                    aval[q] = (short)f2b(v);
                }
            }
            short8 bval = *reinterpret_cast<const short8*>(W + (size_t)(c0 + row) * K + kc + ch * 8);
            __syncthreads();
            int sw = ch ^ ((row >> 1) & 3);
            *reinterpret_cast<short8*>(&Abuf[0][row * 32 + sw * 8]) = aval;
            *reinterpret_cast<short8*>(&Bbuf[0][row * 32 + sw * 8]) = bval;
            __syncthreads();
            short8 af[2], bfr[4];
            #pragma unroll
            for (int m = 0; m < 2; ++m) {
                int rr = wr + m * 16 + rl;
                af[m] = *reinterpret_cast<const short8*>(&Abuf[0][rr * 32 + (kh ^ ((rr >> 1) & 3)) * 8]);
            }
            #pragma unroll
            for (int nn = 0; nn < 4; ++nn) {
                int col = wc + nn * 16 + rl;
                bfr[nn] = *reinterpret_cast<const short8*>(&Bbuf[0][col * 32 + (kh ^ ((col >> 1) & 3)) * 8]);
            }
            #pragma unroll
            for (int m = 0; m < 2; ++m)
                #pragma unroll
                for (int nn = 0; nn < 4; ++nn)
                    acc[m][nn] = __builtin_amdgcn_mfma_f32_16x16x32_bf16(
                        bfr[nn], af[m], acc[m][nn], 0, 0, 0);
        }
    } else {
        const int ch = pos ^ ((row >> 1) & 3);
        const ushort* Abase = (const ushort*)Aptr + (size_t)(r0 + row) * K + ch * 8;
        const ushort* Bbase = W + (size_t)(c0 + row) * K + ch * 8;
        __builtin_amdgcn_global_load_lds(
            (const __attribute__((address_space(1))) void*)Abase,
            (__attribute__((address_space(3))) void*)&Abuf[0][t * 8], 16, 0, 0);
        __builtin_amdgcn_global_load_lds(
            (const __attribute__((address_space(1))) void*)Bbase,
            (__attribute__((address_space(3))) void*)&Bbuf[0][t * 8], 16, 0, 0);
        __syncthreads();
        for (int c = 0; c < nc; ++c) {
            if (c + 1 < nc) {
                int half = (c + 1) & 1;
                __builtin_amdgcn_global_load_lds(
                    (const __attribute__((address_space(1))) void*)(Abase + (c + 1) * 32),
                    (__attribute__((address_space(3))) void*)&Abuf[half][t * 8], 16, 0, 0);
                __builtin_amdgcn_global_load_lds(
                    (const __attribute__((address_space(1))) void*)(Bbase + (c + 1) * 32),
                    (__attribute__((address_space(3))) void*)&Bbuf[half][t * 8], 16, 0, 0);
            }
            const int cur = c & 1;
            short8 af[2], bfr[4];
            #pragma unroll
            for (int m = 0; m < 2; ++m) {
                int rr = wr + m * 16 + rl;
                af[m] = *reinterpret_cast<const short8*>(&Abuf[cur][rr * 32 + (kh ^ ((rr >> 1) & 3)) * 8]);
            }
            #pragma unroll
            for (int nn = 0; nn < 4; ++nn) {
                int col = wc + nn * 16 + rl;
                bfr[nn] = *reinterpret_cast<const short8*>(&Bbuf[cur][col * 32 + (kh ^ ((col >> 1) & 3)) * 8]);
            }
            #pragma unroll
            for (int m = 0; m < 2; ++m)
                #pragma unroll
                for (int nn = 0; nn < 4; ++nn)
                    acc[m][nn] = __builtin_amdgcn_mfma_f32_16x16x32_bf16(
                        bfr[nn], af[m], acc[m][nn], 0, 0, 0);
            __syncthreads();
        }
    }

    const int ch4 = kh * 4;

    if (EPI == 1) {
        __shared__ float lnS[128][2], lnS2[128][2];
        float4 bb[4];
        #pragma unroll
        for (int nn = 0; nn < 4; ++nn)
            bb[nn] = *reinterpret_cast<const float4*>(bias + wc + nn * 16 + ch4);
        #pragma unroll
        for (int m = 0; m < 2; ++m) {
            int r = r0 + wr + m * 16 + rl;
            float s = 0.f, s2 = 0.f;
            #pragma unroll
            for (int nn = 0; nn < 4; ++nn) {
                int c = wc + nn * 16 + ch4;
                float rv[4] = {0.f, 0.f, 0.f, 0.f};
                if (r < n) {
                    if (RESF32) {
                        float4 f = *reinterpret_cast<const float4*>((const float*)resid + (size_t)r * 128 + c);
                        rv[0] = f.x; rv[1] = f.y; rv[2] = f.z; rv[3] = f.w;
                    } else {
                        short4v f = *reinterpret_cast<const short4v*>((const ushort*)resid + (size_t)r * 128 + c);
                        rv[0] = b2f((ushort)f[0]); rv[1] = b2f((ushort)f[1]);
                        rv[2] = b2f((ushort)f[2]); rv[3] = b2f((ushort)f[3]);
                    }
                }
                float bj[4] = {bb[nn].x, bb[nn].y, bb[nn].z, bb[nn].w};
                #pragma unroll
                for (int j = 0; j < 4; ++j) {
                    float o = acc[m][nn][j] + bj[j] + rv[j];
                    acc[m][nn][j] = o;
                    s += o; s2 += o * o;
                }
            }
            s  += __shfl_xor(s, 16);  s  += __shfl_xor(s, 32);
            s2 += __shfl_xor(s2, 16); s2 += __shfl_xor(s2, 32);
            if (kh == 0) {
                lnS[wr + m * 16 + rl][w & 1]  = s;
                lnS2[wr + m * 16 + rl][w & 1] = s2;
            }
        }
        __syncthreads();
        #pragma unroll
        for (int m = 0; m < 2; ++m) {
            int rloc = wr + m * 16 + rl;
            int r = r0 + rloc;
            float S  = lnS[rloc][0] + lnS[rloc][1];
            float S2 = lnS2[rloc][0] + lnS2[rloc][1];
            float mean = S * (1.f / 128.f);
            float var  = S2 * (1.f / 128.f) - mean * mean;
            float rs   = rsqrtf(var + 1e-5f);
            if (r >= n) continue;
            #pragma unroll
            for (int nn = 0; nn < 4; ++nn) {
                int c = wc + nn * 16 + ch4;
                float4 gv = *reinterpret_cast<const float4*>(lng + c);
                float4 bv = *reinterpret_cast<const float4*>(lnb + c);
                float gj[4] = {gv.x, gv.y, gv.z, gv.w};
                float bj[4] = {bv.x, bv.y, bv.z, bv.w};
                short4v p;
                #pragma unroll
                for (int j = 0; j < 4; ++j)
                    p[j] = (short)f2b((acc[m][nn][j] - mean) * rs * gj[j] + bj[j]);
                *reinterpret_cast<short4v*>((ushort*)C + (size_t)r * 128 + c) = p;
            }
        }
        return;
    }

    if (EPI == 2) {
        __shared__ float csum[128], csum2[128];
        if (t < 128) { csum[t] = 0.f; csum2[t] = 0.f; }
        __syncthreads();
        float ps[4][4] = {};
        float ps2[4][4] = {};
        #pragma unroll
        for (int m = 0; m < 2; ++m) {
            int r = r0 + wr + m * 16 + rl;
            bool ok = r < n;
            #pragma unroll
            for (int nn = 0; nn < 4; ++nn) {
                int c = wc + nn * 16 + ch4;
                float4 bb = *reinterpret_cast<const float4*>(bias + c);
                float bj[4] = {bb.x, bb.y, bb.z, bb.w};
                float4 yv = make_float4(0.f, 0.f, 0.f, 0.f);
                if (ok) yv = *reinterpret_cast<const float4*>(y1res + (size_t)r * 128 + c);
                float yj[4] = {yv.x, yv.y, yv.z, yv.w};
                float oj[4];
                #pragma unroll
                for (int j = 0; j < 4; ++j) {
                    float o = 0.f;
                    if (ok) {
                        o = acc[m][nn][j] + bj[j]
                          + fmaf(yj[j], s_sh[c + j], t_sh[c + j]);
                    }
                    ps[nn][j] += o; ps2[nn][j] += o * o;
                    oj[j] = o;
                }
                if (ok) {
                    float4 o4 = make_float4(oj[0], oj[1], oj[2], oj[3]);
                    *reinterpret_cast<float4*>((float*)C + (size_t)r * 128 + c) = o4;
                }
            }
        }
        #pragma unroll
        for (int nn = 0; nn < 4; ++nn)
            #pragma unroll
            for (int j = 0; j < 4; ++j) {
                float a = ps[nn][j], b = ps2[nn][j];
                #pragma unroll
                for (int o2 = 1; o2 < 16; o2 <<= 1) {
                    a += __shfl_xor(a, o2);
                    b += __shfl_xor(b, o2);
                }
                if (rl == 0) {
                    int c = wc + nn * 16 + ch4 + j;
                    atomicAdd(&csum[c], a);
                    atomicAdd(&csum2[c], b);
                }
            }
        __syncthreads();
        if (t < 128) {
            atomicAdd(bn_out + t, csum[t]);
            atomicAdd(bn_out + 128 + t, csum2[t]);
        }
        return;
    }

    // EPI == 0
    #pragma unroll
    for (int m = 0; m < 2; ++m) {
        int r = r0 + wr + m * 16 + rl;
        if (r >= n) continue;
        #pragma unroll
        for (int nn = 0; nn < 4; ++nn) {
            int c = c0 + wc + nn * 16 + ch4;
            f32x4 vacc = acc[m][nn];
            float4 bb = make_float4(0.f, 0.f, 0.f, 0.f);
            if (bias) bb = *reinterpret_cast<const float4*>(bias + c);
            float o0 = vacc[0] + bb.x, o1 = vacc[1] + bb.y;
            float o2 = vacc[2] + bb.z, o3 = vacc[3] + bb.w;
            if (RELU) {
                o0 = fmaxf(o0, 0.f); o1 = fmaxf(o1, 0.f);
                o2 = fmaxf(o2, 0.f); o3 = fmaxf(o3, 0.f);
            }
            short4v p;
            p[0] = (short)f2b(o0); p[1] = (short)f2b(o1);
            p[2] = (short)f2b(o2); p[3] = (short)f2b(o3);
            *reinterpret_cast<short4v*>((ushort*)C + (size_t)r * M + c) = p;
        }
    }
}

// ---------------------------------------------------------------------------
// Fused FFN + LN2: out = LN(x + relu(x@W1^T+b1)@W2^T + b2), 128-row block.
// W1 chunk (64x128) and W2 chunk (128x64) TIME-SHARE one 16KB buffer:
// issue W1 -> bar -> stage1 -> bar -> issue W2 -> bar -> stage2 -> bar.
// LDS = Xs 32K + FF1 16K + Wbuf 16K = 64K -> 2 blocks/CU.
// Numerics identical to r14 (same values, same accumulation order).
// ---------------------------------------------------------------------------
__global__ __launch_bounds__(512) void ffn_ln_kernel(
    const ushort* __restrict__ X,   const ushort* __restrict__ W1g,  // 512x128
    const ushort* __restrict__ W2g,                                   // 128x512
    const float* __restrict__ b1v,  const float* __restrict__ b2v,
    const float* __restrict__ lng,  const float* __restrict__ lnb,
    ushort* __restrict__ out, int n)
{
    __shared__ ushort Xs[128 * 128];      // 32KB, 16 chunks/row, swz &7
    __shared__ ushort FF1[128 * 64];      // 16KB, 8 chunks/row, swz &7 (lnS alias)
    __shared__ ushort Wbuf[64 * 128];     // 16KB, W1c then W2c per chunk

    const int t    = threadIdx.x;
    const int lane = t & 63;
    const int w    = t >> 6;
    const int r0   = blockIdx.x * 128;
    const int rl   = lane & 15;
    const int kh   = lane >> 4;
    const int wr   = (w >> 1) * 32;       // row group (both stages)
    const int wc1  = (w & 1) * 32;        // stage1 col group (of 64-chunk)
    const int wc2  = (w & 1) * 64;        // stage2 col group (of 128)

    // ---- prologue: X tile ----
    #pragma unroll
    for (int i = 0; i < 4; ++i) {
        int s = t + i * 512;
        int row = s >> 4, pos = s & 15;
        int srcch = pos ^ ((row >> 1) & 7);
        if (r0 + row < n)
            __builtin_amdgcn_global_load_lds(
                (const __attribute__((address_space(1))) void*)(X + (size_t)(r0 + row) * 128 + srcch * 8),
                (__attribute__((address_space(3))) void*)&Xs[s * 8], 16, 0, 0);
    }
    __syncthreads();

    f32x4 acc2[2][4] = {};

    for (int c = 0; c < 8; ++c) {
        // ---- W1 chunk c (64x128) -> Wbuf (prev stage2's Wbuf reads fenced) ----
        #pragma unroll
        for (int i = 0; i < 2; ++i) {
            int s = t + i * 512;
            int row = s >> 4, pos = s & 15;
            int srcch = pos ^ ((row >> 1) & 7);
            __builtin_amdgcn_global_load_lds(
                (const __attribute__((address_space(1))) void*)(W1g + (size_t)(c * 64 + row) * 128 + srcch * 8),
                (__attribute__((address_space(3))) void*)&Wbuf[s * 8], 16, 0, 0);
        }
        __syncthreads();   // W1 landed

        // ---- stage 1: ff1 chunk = relu(x @ W1c^T + b1c), 128x64 (wave 32x32)
        f32x4 acc1[2][2] = {};
        #pragma unroll
        for (int ks = 0; ks < 4; ++ks) {
            int chn = ks * 4 + kh;
            short8 af[2], bf[2];
            #pragma unroll
            for (int m = 0; m < 2; ++m) {
                int row = wr + m * 16 + rl;
                af[m] = *reinterpret_cast<const short8*>(&Xs[row * 128 + (chn ^ ((row >> 1) & 7)) * 8]);
            }
            #pragma unroll
            for (int nn = 0; nn < 2; ++nn) {
                int colL = wc1 + nn * 16 + rl;
                bf[nn] = *reinterpret_cast<const short8*>(&Wbuf[colL * 128 + (chn ^ ((colL >> 1) & 7)) * 8]);
            }
            #pragma unroll
            for (int m = 0; m < 2; ++m)
                #pragma unroll
                for (int nn = 0; nn < 2; ++nn)
                    acc1[m][nn] = __builtin_amdgcn_mfma_f32_16x16x32_bf16(
                        bf[nn], af[m], acc1[m][nn], 0, 0, 0);
        }
        #pragma unroll
        for (int m = 0; m < 2; ++m) {
            int row = wr + m * 16 + rl;
            #pragma unroll
            for (int nn = 0; nn < 2; ++nn) {
                int colL = wc1 + nn * 16 + kh * 4;
                float4 bb = *reinterpret_cast<const float4*>(b1v + c * 64 + colL);
                short4v p;
                p[0] = (short)f2b(fmaxf(acc1[m][nn][0] + bb.x, 0.f));
                p[1] = (short)f2b(fmaxf(acc1[m][nn][1] + bb.y, 0.f));
                p[2] = (short)f2b(fmaxf(acc1[m][nn][2] + bb.z, 0.f));
                p[3] = (short)f2b(fmaxf(acc1[m][nn][3] + bb.w, 0.f));
                int chn = colL >> 3, half = (colL >> 2) & 1;
                *reinterpret_cast<short4v*>(
                    &FF1[row * 64 + (chn ^ ((row >> 1) & 7)) * 8 + half * 4]) = p;
            }
        }
        __syncthreads();   // stage1 Wbuf reads done; FF1 visible

        // ---- W2 chunk c (128x64) -> Wbuf ----
        #pragma unroll
        for (int i = 0; i < 2; ++i) {
            int s = t + i * 512;
            int row = s >> 3, pos = s & 7;
            int srcch = pos ^ ((row >> 1) & 7);
            __builtin_amdgcn_global_load_lds(
                (const __attribute__((address_space(1))) void*)(W2g + (size_t)row * 512 + c * 64 + srcch * 8),
                (__attribute__((address_space(3))) void*)&Wbuf[s * 8], 16, 0, 0);
        }
        __syncthreads();   // W2 landed

        // ---- stage 2: acc2 += ff1c @ W2c^T, 128x128 (wave 32x64), K=64
        #pragma unroll
        for (int ks = 0; ks < 2; ++ks) {
            int chn = ks * 4 + kh;
            short8 af[2], bf[4];
            #pragma unroll
            for (int m = 0; m < 2; ++m) {
                int row = wr + m * 16 + rl;
                af[m] = *reinterpret_cast<const short8*>(&FF1[row * 64 + (chn ^ ((row >> 1) & 7)) * 8]);
            }
            #pragma unroll
            for (int nn = 0; nn < 4; ++nn) {
                int col = wc2 + nn * 16 + rl;
                bf[nn] = *reinterpret_cast<const short8*>(&Wbuf[col * 64 + (chn ^ ((col >> 1) & 7)) * 8]);
            }
            #pragma unroll
            for (int m = 0; m < 2; ++m)
                #pragma unroll
                for (int nn = 0; nn < 4; ++nn)
                    acc2[m][nn] = __builtin_amdgcn_mfma_f32_16x16x32_bf16(
                        bf[nn], af[m], acc2[m][nn], 0, 0, 0);
        }
        __syncthreads();   // stage2 reads done -> Wbuf/FF1 reusable
    }

    // ---- epilogue: LN(x + acc2 + b2) -> out (residual x from LDS) ----
    float* lnSf  = (float*)FF1;          // alias (dead; fenced by last barrier)
    float* lnS2f = lnSf + 256;
    const int ch4 = kh * 4;
    #pragma unroll
    for (int m = 0; m < 2; ++m) {
        int rloc = wr + m * 16 + rl;
        float s = 0.f, s2 = 0.f;
        #pragma unroll
        for (int nn = 0; nn < 4; ++nn) {
            int col = wc2 + nn * 16 + ch4;
            int chn = col >> 3;
            short4v xv = *reinterpret_cast<const short4v*>(
                &Xs[rloc * 128 + (chn ^ ((rloc >> 1) & 7)) * 8 + ((col >> 2) & 1) * 4]);
            float4 bb = *reinterpret_cast<const float4*>(b2v + col);
            float bj[4] = {bb.x, bb.y, bb.z, bb.w};
            #pragma unroll
            for (int j = 0; j < 4; ++j) {
                float o = acc2[m][nn][j] + bj[j] + b2f((ushort)xv[j]);
                acc2[m][nn][j] = o;
                s += o; s2 += o * o;
            }
        }
        s  += __shfl_xor(s, 16);  s  += __shfl_xor(s, 32);
        s2 += __shfl_xor(s2, 16); s2 += __shfl_xor(s2, 32);
        if (kh == 0) {
            lnSf[rloc * 2 + (w & 1)]  = s;
            lnS2f[rloc * 2 + (w & 1)] = s2;
        }
    }
    __syncthreads();
    #pragma unroll
    for (int m = 0; m < 2; ++m) {
        int rloc = wr + m * 16 + rl;
        int r = r0 + rloc;
        float S  = lnSf[rloc * 2 + 0] + lnSf[rloc * 2 + 1];
        float S2 = lnS2f[rloc * 2 + 0] + lnS2f[rloc * 2 + 1];
        float mean = S * (1.f / 128.f);
        float var  = S2 * (1.f / 128.f) - mean * mean;
        float rs   = rsqrtf(var + 1e-5f);
        if (r >= n) continue;
        #pragma unroll
        for (int nn = 0; nn < 4; ++nn) {
            int col = wc2 + nn * 16 + ch4;
            float4 gv = *reinterpret_cast<const float4*>(lng + col);
            float4 bv = *reinterpret_cast<const float4*>(lnb + col);
            float gj[4] = {gv.x, gv.y, gv.z, gv.w};
            float bj[4] = {bv.x, bv.y, bv.z, bv.w};
            short4v p;
            #pragma unroll
            for (int j = 0; j < 4; ++j)
                p[j] = (short)f2b((acc2[m][nn][j] - mean) * rs * gj[j] + bj[j]);
            *reinterpret_cast<short4v*>(out + (size_t)r * 128 + col) = p;
        }
    }
}

// ---------------------------------------------------------------------------
__global__ __launch_bounds__(256) void zero_kernel(int4* __restrict__ p, int n4)
{
    int i = blockIdx.x * blockDim.x + threadIdx.x;
    int stride = gridDim.x * blockDim.x;
    int4 z = make_int4(0, 0, 0, 0);
    for (; i < n4; i += stride) p[i] = z;
}

// ---------------------------------------------------------------------------
// Merged histogram + weight prep
// ---------------------------------------------------------------------------
struct WPtrs { const float* p[7]; };

__global__ __launch_bounds__(256) void hist_prep_kernel(
    const int* __restrict__ dst, int* __restrict__ cnt, int E_, int Eb,
    const float* __restrict__ Win, const float* __restrict__ bin_,
    const float* __restrict__ Wout, const float* __restrict__ bout,
    WPtrs wp, ushort* __restrict__ wbf, float* __restrict__ bfused)
{
    int blk = blockIdx.x;
    if (blk < Eb) {
        int e = blk * 256 + threadIdx.x;
        if (e < E_) atomicAdd(cnt + dst[e], 1);
        return;
    }
    int b = blk - Eb;
    if (b < 64) {
        int idx = b * 256 + threadIdx.x;
        int i = idx >> 7, c = idx & 127;
        const float* WinV = Win + 256 * 128;
        float s = 0.f;
        for (int j = 0; j < 128; ++j)
            s = fmaf(Wout[i * 128 + j], WinV[j * 128 + c], s);
        wbf[245760 + idx] = f2b(s);
        if (c == 0) {
            float tb = bout[i];
            for (int j = 0; j < 128; ++j)
                tb = fmaf(Wout[i * 128 + j], bin_[256 + j], tb);
            bfused[i] = tb;
        }
    } else {
        const int off[8] = {0, 65536, 131072, 147456, 163840, 180224, 212992, 245760};
        int e0 = ((b - 64) * 256 + threadIdx.x) * 4;
        if (e0 >= 245760) return;
        int s = 0;
        #pragma unroll
        for (int j = 1; j < 7; ++j) if (e0 >= off[j]) s = j;
        float4 f = *reinterpret_cast<const float4*>(wp.p[s] + (e0 - off[s]));
        short4v o;
        o[0] = (short)f2b(f.x); o[1] = (short)f2b(f.y);
        o[2] = (short)f2b(f.z); o[3] = (short)f2b(f.w);
        *reinterpret_cast<short4v*>(wbf + e0) = o;
    }
}

__global__ __launch_bounds__(256) void scan_block_kernel(
    int* __restrict__ data, int* __restrict__ bsum, int n)
{
    __shared__ int tmp[256];
    int i = blockIdx.x * 256 + threadIdx.x;
    int v = (i < n) ? data[i] : 0;
    tmp[threadIdx.x] = v;
    __syncthreads();
    #pragma unroll
    for (int o = 1; o < 256; o <<= 1) {
        int y = (threadIdx.x >= o) ? tmp[threadIdx.x - o] : 0;
        __syncthreads();
        tmp[threadIdx.x] += y;
        __syncthreads();
    }
    if (i < n) data[i] = tmp[threadIdx.x] - v;
    if (threadIdx.x == 255) bsum[blockIdx.x] = tmp[255];
}

__global__ __launch_bounds__(256) void add_off_kernel(
    int* __restrict__ data, const int* __restrict__ bsum, int n, int nb)
{
    __shared__ int red[4];
    int b = blockIdx.x;
    int v = (threadIdx.x < b && threadIdx.x < nb) ? bsum[threadIdx.x] : 0;
    #pragma unroll
    for (int o = 1; o < 64; o <<= 1) v += __shfl_xor(v, o);
    if ((threadIdx.x & 63) == 0) red[threadIdx.x >> 6] = v;
    __syncthreads();
    int off = red[0] + red[1] + red[2] + red[3];
    int i = b * 256 + threadIdx.x;
    if (i < n) data[i] += off;
}

__global__ void scatter_kernel(const int* __restrict__ src, const int* __restrict__ dst,
                               int* __restrict__ rowptr, int* __restrict__ csr_src, int E_)
{
    int e = blockIdx.x * blockDim.x + threadIdx.x;
    if (e >= E_) return;
    int pos = atomicAdd(rowptr + dst[e], 1);
    csr_src[pos] = src[e];
}

// ---------------------------------------------------------------------------
// Gather attention: 32 lanes/node = 4 edge-slots x 8 heads (proven shape).
// Writes y1 = hsub + wV/z as FLOAT32.
// ---------------------------------------------------------------------------
__global__ __launch_bounds__(256) void attn_agg_kernel(
    const int* __restrict__ rowptr, const int* __restrict__ csr_src,
    const ushort* __restrict__ QKV, const ushort* __restrict__ hsub,
    float* __restrict__ out, int n)
{
    int node  = (blockIdx.x * blockDim.x + threadIdx.x) >> 5;
    int lane5 = threadIdx.x & 31;
    int slot  = lane5 >> 3;   // 0..3
    int hd    = lane5 & 7;    // head; channels [16*hd, 16*hd+16)
    bool valid = node < n;
    int nd = valid ? node : 0;
    int start = (valid && nd) ? rowptr[nd - 1] : 0;
    int end   = valid ? rowptr[nd] : 0;

    const ushort* qp = QKV + (size_t)nd * 384 + hd * 16;
    short8 q0 = *reinterpret_cast<const short8*>(qp);
    short8 q1 = *reinterpret_cast<const short8*>(qp + 8);
    float q[16];
    #pragma unroll
    for (int i = 0; i < 8; ++i) { q[i] = b2f((ushort)q0[i]); q[8 + i] = b2f((ushort)q1[i]); }

    float acc[16] = {};
    float zh = 0.f;
    for (int j = start; j < end; j += 4) {
        int idx = j + slot;
        if (idx < end) {
            int s = csr_src[idx];
            const ushort* kp = QKV + (size_t)s * 384 + 128 + hd * 16;
            short8 k0 = *reinterpret_cast<const short8*>(kp);
            short8 k1 = *reinterpret_cast<const short8*>(kp + 8);
            float p = 0.f;
            #pragma unroll
            for (int i = 0; i < 8; ++i) {
                p = fmaf(b2f((ushort)k0[i]), q[i], p);
                p = fmaf(b2f((ushort)k1[i]), q[8 + i], p);
            }
            float sc = __expf(fminf(fmaxf(p * 0.25f, -5.f), 5.f));
            short8 v0 = *reinterpret_cast<const short8*>(kp + 128);
            short8 v1 = *reinterpret_cast<const short8*>(kp + 136);
            #pragma unroll
            for (int i = 0; i < 8; ++i) {
                acc[i]     = fmaf(sc, b2f((ushort)v0[i]), acc[i]);
                acc[8 + i] = fmaf(sc, b2f((ushort)v1[i]), acc[8 + i]);
            }
            zh += sc;
        }
    }
    #pragma unroll
    for (int i = 0; i < 16; ++i) {
        acc[i] += __shfl_xor(acc[i], 8);
        acc[i] += __shfl_xor(acc[i], 16);
    }
    zh += __shfl_xor(zh, 8);
    zh += __shfl_xor(zh, 16);

    if (slot == 0 && valid) {
        const ushort* hp = hsub + (size_t)nd * D_ + hd * 16;
        short8 h0 = *reinterpret_cast<const short8*>(hp);
        short8 h1 = *reinterpret_cast<const short8*>(hp + 8);
        float inv = 1.f / zh;
        float* op = out + (size_t)nd * D_ + hd * 16;
        float4 o;
        o.x = b2f((ushort)h0[0]) + acc[0] * inv;
        o.y = b2f((ushort)h0[1]) + acc[1] * inv;
        o.z = b2f((ushort)h0[2]) + acc[2] * inv;
        o.w = b2f((ushort)h0[3]) + acc[3] * inv;
        reinterpret_cast<float4*>(op)[0] = o;
        o.x = b2f((ushort)h0[4]) + acc[4] * inv;
        o.y = b2f((ushort)h0[5]) + acc[5] * inv;
        o.z = b2f((ushort)h0[6]) + acc[6] * inv;
        o.w = b2f((ushort)h0[7]) + acc[7] * inv;
        reinterpret_cast<float4*>(op)[1] = o;
        o.x = b2f((ushort)h1[0]) + acc[8]  * inv;
        o.y = b2f((ushort)h1[1]) + acc[9]  * inv;
        o.z = b2f((ushort)h1[2]) + acc[10] * inv;
        o.w = b2f((ushort)h1[3]) + acc[11] * inv;
        reinterpret_cast<float4*>(op)[2] = o;
        o.x = b2f((ushort)h1[4]) + acc[12] * inv;
        o.y = b2f((ushort)h1[5]) + acc[13] * inv;
        o.z = b2f((ushort)h1[6]) + acc[14] * inv;
        o.w = b2f((ushort)h1[7]) + acc[15] * inv;
        reinterpret_cast<float4*>(op)[3] = o;
    }
}

// ---------------------------------------------------------------------------
// BN stats over FLOAT input: sums[c], sums[128+c].
// ---------------------------------------------------------------------------
__global__ __launch_bounds__(256) void bn_stats_kernel(
    const float* __restrict__ x, float* __restrict__ sums, int n)
{
    int c    = threadIdx.x & 127;
    int half = threadIdx.x >> 7;
    float s = 0.f, s2 = 0.f;
    for (int r = blockIdx.x * 2 + half; r < n; r += gridDim.x * 2) {
        float v = x[(size_t)r * D_ + c];
        s += v; s2 += v * v;
    }
    __shared__ float ls[256], ls2[256];
    ls[threadIdx.x] = s; ls2[threadIdx.x] = s2;
    __syncthreads();
    if (half == 0) {
        s  += ls[threadIdx.x + 128];
        s2 += ls2[threadIdx.x + 128];
        atomicAdd(sums + c, s);
        atomicAdd(sums + 128 + c, s2);
    }
}

// final BN: FLOAT in -> f32 out, 4 elems/thread
__global__ void bn_norm_kernel(const float* __restrict__ x,
                               const float* __restrict__ stats,
                               const float* __restrict__ g, const float* __restrict__ b,
                               float* __restrict__ out, float invn, int total4)
{
    int i = blockIdx.x * blockDim.x + threadIdx.x;
    if (i >= total4) return;
    int cb = (i << 2) & 127;
    float4 v = reinterpret_cast<const float4*>(x)[i];
    float vj[4] = {v.x, v.y, v.z, v.w};
    float r[4];
    #pragma unroll
    for (int q = 0; q < 4; ++q) {
        int c = cb + q;
        float m   = stats[c] * invn;
        float var = stats[128 + c] * invn - m * m;
        float rs  = rsqrtf(var + 1e-5f);
        r[q] = (vj[q] - m) * rs * g[c] + b[c];
    }
    float4 o; o.x = r[0]; o.y = r[1]; o.z = r[2]; o.w = r[3];
    reinterpret_cast<float4*>(out)[i] = o;
}

// ---------------------------------------------------------------------------
extern "C" void kernel_launch(void* const* d_in, const int* in_sizes, int n_in,
                              void* d_out, int out_size, void* d_ws, size_t ws_size,
                              hipStream_t stream)
{
    const float* h    = (const float*)d_in[0];
    const int*   src  = (const int*)d_in[1];
    const int*   dst  = (const int*)d_in[2];
    const float* Win  = (const float*)d_in[3];
    const float* bin_ = (const float*)d_in[4];
    const float* Wout = (const float*)d_in[5];
    const float* bout = (const float*)d_in[6];
    const float* Wte1 = (const float*)d_in[7];
    const float* bte1 = (const float*)d_in[8];
    const float* Wte2 = (const float*)d_in[9];
    const float* bte2 = (const float*)d_in[10];
    const float* ln1g = (const float*)d_in[11];
    const float* ln1b = (const float*)d_in[12];
    const float* ln2g = (const float*)d_in[13];
    const float* ln2b = (const float*)d_in[14];
    const float* WQ   = (const float*)d_in[15];
    const float* WK   = (const float*)d_in[16];
    const float* WV   = (const float*)d_in[17];
    const float* W1   = (const float*)d_in[18];
    const float* b1   = (const float*)d_in[19];
    const float* W2   = (const float*)d_in[20];
    const float* b2   = (const float*)d_in[21];
    const float* bn1g = (const float*)d_in[22];
    const float* bn1b = (const float*)d_in[23];
    const float* bn2g = (const float*)d_in[24];
    const float* bn2b = (const float*)d_in[25];

    const int N_ = in_sizes[0] / D_;
    const int E_ = in_sizes[1];
    const size_t S2 = (size_t)N_ * D_ / 2;   // float units of one NxD bf16 buffer

    float* ws = (float*)d_ws;
    size_t off_tail = 10 * S2;
    size_t need = (off_tail + 131072 + 128 + 512) * sizeof(float)
                + (size_t)(N_ + E_ + 256) * sizeof(int) + 4096;
    if (ws_size < need) return;

    ushort* bufA   = (ushort*)ws;                 // x (bf16)
    ushort* bufC   = (ushort*)(ws + S2);          // hsub (bf16)
    ushort* bufD   = (ushort*)(ws + 2 * S2);      // QKV / f1 (bf16)
    float*  y1f    = ws + 6 * S2;
    float*  y2f    = ws + 8 * S2;
    ushort* wbf    = (ushort*)(ws + off_tail);
    float*  bfused = ws + off_tail + 131072;
    float*  stats  = bfused + 128;
    int* rowptr  = (int*)(stats + 512);
    int* csr_src = rowptr + N_;
    int* bsum    = csr_src + E_;

    const ushort* Wte1_bf = wbf;
    const ushort* Wte2_bf = wbf + 65536;
    const ushort* WQKV_bf = wbf + 131072;
    const ushort* W1_bf   = wbf + 180224;
    const ushort* W2_bf   = wbf + 212992;
    ushort*       Wf_bf   = wbf + 245760;

    dim3 blk(256);
    dim3 blk512(512);
    const int rowBlocks = (N_ + 127) / 128;
    const int totElems  = N_ * D_;
    const dim3 gNode((N_ + 7) / 8);               // 8 nodes/block (32 lanes/node)
    const int nb = (N_ + 255) / 256;
    const int Eb = (E_ + 255) / 256;
    const float invn = 1.f / (float)N_;

    {
        int n4 = (512 + N_) / 4;
        int zblocks = (n4 + 255) / 256;
        if (zblocks > 128) zblocks = 128;
        zero_kernel<<<dim3(zblocks), blk, 0, stream>>>((int4*)stats, n4);
    }

    // --- CSR build + weight prep (merged) ---
    WPtrs wp;
    wp.p[0] = Wte1; wp.p[1] = Wte2; wp.p[2] = WQ; wp.p[3] = WK; wp.p[4] = WV;
    wp.p[5] = W1;   wp.p[6] = W2;
    hist_prep_kernel<<<dim3(Eb + 304), blk, 0, stream>>>(
        dst, rowptr, E_, Eb, Win, bin_, Wout, bout, wp, wbf, bfused);
    scan_block_kernel<<<dim3(nb), blk, 0, stream>>>(rowptr, bsum, N_);
    add_off_kernel<<<dim3(nb), blk, 0, stream>>>(rowptr, bsum, N_, nb);
    scatter_kernel<<<dim3(Eb), blk, 0, stream>>>(src, dst, rowptr, csr_src, E_);

    // --- per-node TransformerEncoder ---
    gemm_bf16<1, 1, false, true><<<dim3(rowBlocks, 1), blk512, 0, stream>>>(
        h, Wf_bf, bfused, bufA, nullptr, nullptr, nullptr, nullptr,
        h, nullptr, ln1g, ln1b, 0.f, N_, 128, 128);
    ffn_ln_kernel<<<dim3(rowBlocks), blk512, 0, stream>>>(
        bufA, Wte1_bf, Wte2_bf, bte1, bte2, ln2g, ln2b, bufC, N_);

    // --- graph multi-head attention ---
    gemm_bf16<0, 0, false, false><<<dim3(rowBlocks, 3), blk512, 0, stream>>>(
        bufC, WQKV_bf, nullptr, bufD, nullptr, nullptr, nullptr, nullptr,
        nullptr, nullptr, nullptr, nullptr, 0.f, N_, 128, 384);
    attn_agg_kernel<<<gNode, blk, 0, stream>>>(
        rowptr, csr_src, bufD, bufC, y1f, N_);                           // y1 (f32)

    // --- BN1 stats ---
    bn_stats_kernel<<<dim3(512), blk, 0, stream>>>(y1f, stats, N_);

    // --- FFN + BN2 ---
    gemm_bf16<3, 0, true, false><<<dim3(rowBlocks, 2), blk512, 0, stream>>>(
        y1f, W1_bf, b1, bufD, stats, nullptr, bn1g, bn1b,
        nullptr, nullptr, nullptr, nullptr, invn, N_, 128, 256);
    gemm_bf16<0, 2, false, false><<<dim3(rowBlocks, 1), blk512, 0, stream>>>(
        bufD, W2_bf, b2, y2f, stats, stats + 256, bn1g, bn1b,
        nullptr, y1f, nullptr, nullptr, invn, N_, 256, 128);
    bn_norm_kernel<<<dim3((totElems / 4 + 255) / 256), blk, 0, stream>>>(
        y2f, stats + 256, bn2g, bn2b, (float*)d_out, invn, totElems / 4);
}

// Round 17
// 250.483 us; speedup vs baseline: 1.1827x; 1.0237x over previous
//
#include <hip/hip_runtime.h>
#include <hip/hip_bf16.h>

// GraphTransformerLayer on MI355X — round 17: best-of consolidation.
// r12's bf16 y1/y2 chain (f32 paths bought no margin, cost ~5us) +
// r16's W-timeshare ffn_ln (64KB LDS, 2 blocks/CU) + merged hist_prep.
// N=50000, E=500000, D=128, H=8, DH=16.

#define D_ 128

typedef __attribute__((ext_vector_type(8))) short short8;
typedef __attribute__((ext_vector_type(4))) short short4v;
typedef __attribute__((ext_vector_type(4))) float f32x4;

__device__ __forceinline__ float b2f(ushort u) {
    union { uint u32; float f; } x; x.u32 = ((uint)u) << 16; return x.f;
}
__device__ __forceinline__ ushort f2b(float f) {
    union { __hip_bfloat16 h; ushort u; } v; v.h = __float2bfloat16(f); return v.u;
}

// ---------------------------------------------------------------------------
// bf16 MFMA GEMM (r12's proven template): C[n x M] = A[n x K] @ W[M x K]^T
// AMODE 0: A bf16 via global_load_lds, 2-phase prefetch
//       1: A f32 reg-staged with convert (single buffer)
//       2: A bf16 via global_load_lds + BN1 normalize at fragment read (K=128)
// EPI   0: bf16 store (+bias,+relu)
//       1: LN(resid + acc + bias) row-norm -> bf16 (M=128, grid.y=1)
//       2: y2 = acc + bias + BN1(y1res bf16) -> bf16 store + BN2 stats (M=128)
// ---------------------------------------------------------------------------
template<int AMODE, int EPI, bool RELU, bool RESF32>
__global__ __launch_bounds__(512) void gemm_bf16(
    const void* __restrict__ Aptr, const ushort* __restrict__ W,
    const float* __restrict__ bias, void* __restrict__ C,
    const float* __restrict__ bn_in, float* __restrict__ bn_out,
    const float* __restrict__ bng, const float* __restrict__ bnb,
    const void* __restrict__ resid, const ushort* __restrict__ y1res,
    const float* __restrict__ lng, const float* __restrict__ lnb,
    float invn, int n, int K, int M)
{
    __shared__ ushort Abuf[2][128 * 32];
    __shared__ ushort Bbuf[2][128 * 32];
    __shared__ float s_sh[128], t_sh[128];

    const int t    = threadIdx.x;
    const int lane = t & 63;
    const int w    = t >> 6;
    const int r0   = blockIdx.x * 128;
    const int c0   = blockIdx.y * 128;
    const int wr   = (w >> 1) * 32;
    const int wc   = (w & 1) * 64;
    const int rl   = lane & 15;
    const int kh   = lane >> 4;

    if (AMODE == 2 || EPI == 2) {
        if (t < 128) {
            float m   = bn_in[t] * invn;
            float var = bn_in[128 + t] * invn - m * m;
            float rs  = rsqrtf(var + 1e-5f);
            float s   = rs * bng[t];
            s_sh[t] = s;
            t_sh[t] = bnb[t] - m * s;
        }
        __syncthreads();
    }

    f32x4 acc[2][4] = {};
    const int nc = K >> 5;
    const int row = t >> 2, pos = t & 3;

    if (AMODE == 1) {
        for (int c = 0; c < nc; ++c) {
            int kc = c * 32;
            const int ch = pos;
            int gr = r0 + row;
            short8 aval = {};
            if (gr < n) {
                const float* Af = (const float*)Aptr;
                float4 f0 = *reinterpret_cast<const float4*>(Af + (size_t)gr * K + kc + ch * 8);
                float4 f1 = *reinterpret_cast<const float4*>(Af + (size_t)gr * K + kc + ch * 8 + 4);
                aval[0] = (short)f2b(f0.x); aval[1] = (short)f2b(f0.y);
                aval[2] = (short)f2b(f0.z); aval[3] = (short)f2b(f0.w);
                aval[4] = (short)f2b(f1.x); aval[5] = (short)f2b(f1.y);
                aval[6] = (short)f2b(f1.z); aval[7] = (short)f2b(f1.w);
            }
            short8 bval = *reinterpret_cast<const short8*>(W + (size_t)(c0 + row) * K + kc + ch * 8);
            __syncthreads();
            int sw = ch ^ ((row >> 1) & 3);
            *reinterpret_cast<short8*>(&Abuf[0][row * 32 + sw * 8]) = aval;
            *reinterpret_cast<short8*>(&Bbuf[0][row * 32 + sw * 8]) = bval;
            __syncthreads();
            short8 af[2], bfr[4];
            #pragma unroll
            for (int m = 0; m < 2; ++m) {
                int rr = wr + m * 16 + rl;
                af[m] = *reinterpret_cast<const short8*>(&Abuf[0][rr * 32 + (kh ^ ((rr >> 1) & 3)) * 8]);
            }
            #pragma unroll
            for (int nn = 0; nn < 4; ++nn) {
                int col = wc + nn * 16 + rl;
                bfr[nn] = *reinterpret_cast<const short8*>(&Bbuf[0][col * 32 + (kh ^ ((col >> 1) & 3)) * 8]);
            }
            #pragma unroll
            for (int m = 0; m < 2; ++m)
                #pragma unroll
                for (int nn = 0; nn < 4; ++nn)
                    acc[m][nn] = __builtin_amdgcn_mfma_f32_16x16x32_bf16(
                        bfr[nn], af[m], acc[m][nn], 0, 0, 0);
        }
    } else {
        const int ch = pos ^ ((row >> 1) & 3);
        const ushort* Abase = (const ushort*)Aptr + (size_t)(r0 + row) * K + ch * 8;
        const ushort* Bbase = W + (size_t)(c0 + row) * K + ch * 8;
        __builtin_amdgcn_global_load_lds(
            (const __attribute__((address_space(1))) void*)Abase,
            (__attribute__((address_space(3))) void*)&Abuf[0][t * 8], 16, 0, 0);
        __builtin_amdgcn_global_load_lds(
            (const __attribute__((address_space(1))) void*)Bbase,
            (__attribute__((address_space(3))) void*)&Bbuf[0][t * 8], 16, 0, 0);
        __syncthreads();
        for (int c = 0; c < nc; ++c) {
            if (c + 1 < nc) {
                int half = (c + 1) & 1;
                __builtin_amdgcn_global_load_lds(
                    (const __attribute__((address_space(1))) void*)(Abase + (c + 1) * 32),
                    (__attribute__((address_space(3))) void*)&Abuf[half][t * 8], 16, 0, 0);
                __builtin_amdgcn_global_load_lds(
                    (const __attribute__((address_space(1))) void*)(Bbase + (c + 1) * 32),
                    (__attribute__((address_space(3))) void*)&Bbuf[half][t * 8], 16, 0, 0);
            }
            const int cur = c & 1;
            const int kc  = c * 32;
            short8 af[2], bfr[4];
            #pragma unroll
            for (int m = 0; m < 2; ++m) {
                int rr = wr + m * 16 + rl;
                af[m] = *reinterpret_cast<const short8*>(&Abuf[cur][rr * 32 + (kh ^ ((rr >> 1) & 3)) * 8]);
            }
            if (AMODE == 2) {
                #pragma unroll
                for (int m = 0; m < 2; ++m) {
                    short8 v = af[m];
                    #pragma unroll
                    for (int q = 0; q < 8; ++q) {
                        int cch = kc + kh * 8 + q;
                        v[q] = (short)f2b(fmaf(b2f((ushort)v[q]), s_sh[cch], t_sh[cch]));
                    }
                    af[m] = v;
                }
            }
            #pragma unroll
            for (int nn = 0; nn < 4; ++nn) {
                int col = wc + nn * 16 + rl;
                bfr[nn] = *reinterpret_cast<const short8*>(&Bbuf[cur][col * 32 + (kh ^ ((col >> 1) & 3)) * 8]);
            }
            #pragma unroll
            for (int m = 0; m < 2; ++m)
                #pragma unroll
                for (int nn = 0; nn < 4; ++nn)
                    acc[m][nn] = __builtin_amdgcn_mfma_f32_16x16x32_bf16(
                        bfr[nn], af[m], acc[m][nn], 0, 0, 0);
            __syncthreads();
        }
    }

    const int ch4 = kh * 4;

    if (EPI == 1) {
        __shared__ float lnS[128][2], lnS2[128][2];
        float4 bb[4];
        #pragma unroll
        for (int nn = 0; nn < 4; ++nn)
            bb[nn] = *reinterpret_cast<const float4*>(bias + wc + nn * 16 + ch4);
        #pragma unroll
        for (int m = 0; m < 2; ++m) {
            int r = r0 + wr + m * 16 + rl;
            float s = 0.f, s2 = 0.f;
            #pragma unroll
            for (int nn = 0; nn < 4; ++nn) {
                int c = wc + nn * 16 + ch4;
                float rv[4] = {0.f, 0.f, 0.f, 0.f};
                if (r < n) {
                    if (RESF32) {
                        float4 f = *reinterpret_cast<const float4*>((const float*)resid + (size_t)r * 128 + c);
                        rv[0] = f.x; rv[1] = f.y; rv[2] = f.z; rv[3] = f.w;
                    } else {
                        short4v f = *reinterpret_cast<const short4v*>((const ushort*)resid + (size_t)r * 128 + c);
                        rv[0] = b2f((ushort)f[0]); rv[1] = b2f((ushort)f[1]);
                        rv[2] = b2f((ushort)f[2]); rv[3] = b2f((ushort)f[3]);
                    }
                }
                float bj[4] = {bb[nn].x, bb[nn].y, bb[nn].z, bb[nn].w};
                #pragma unroll
                for (int j = 0; j < 4; ++j) {
                    float o = acc[m][nn][j] + bj[j] + rv[j];
                    acc[m][nn][j] = o;
                    s += o; s2 += o * o;
                }
            }
            s  += __shfl_xor(s, 16);  s  += __shfl_xor(s, 32);
            s2 += __shfl_xor(s2, 16); s2 += __shfl_xor(s2, 32);
            if (kh == 0) {
                lnS[wr + m * 16 + rl][w & 1]  = s;
                lnS2[wr + m * 16 + rl][w & 1] = s2;
            }
        }
        __syncthreads();
        #pragma unroll
        for (int m = 0; m < 2; ++m) {
            int rloc = wr + m * 16 + rl;
            int r = r0 + rloc;
            float S  = lnS[rloc][0] + lnS[rloc][1];
            float S2 = lnS2[rloc][0] + lnS2[rloc][1];
            float mean = S * (1.f / 128.f);
            float var  = S2 * (1.f / 128.f) - mean * mean;
            float rs   = rsqrtf(var + 1e-5f);
            if (r >= n) continue;
            #pragma unroll
            for (int nn = 0; nn < 4; ++nn) {
                int c = wc + nn * 16 + ch4;
                float4 gv = *reinterpret_cast<const float4*>(lng + c);
                float4 bv = *reinterpret_cast<const float4*>(lnb + c);
                float gj[4] = {gv.x, gv.y, gv.z, gv.w};
                float bj[4] = {bv.x, bv.y, bv.z, bv.w};
                short4v p;
                #pragma unroll
                for (int j = 0; j < 4; ++j)
                    p[j] = (short)f2b((acc[m][nn][j] - mean) * rs * gj[j] + bj[j]);
                *reinterpret_cast<short4v*>((ushort*)C + (size_t)r * 128 + c) = p;
            }
        }
        return;
    }

    if (EPI == 2) {
        __shared__ float csum[128], csum2[128];
        if (t < 128) { csum[t] = 0.f; csum2[t] = 0.f; }
        __syncthreads();
        float ps[4][4] = {};
        float ps2[4][4] = {};
        #pragma unroll
        for (int m = 0; m < 2; ++m) {
            int r = r0 + wr + m * 16 + rl;
            bool ok = r < n;
            #pragma unroll
            for (int nn = 0; nn < 4; ++nn) {
                int c = wc + nn * 16 + ch4;
                float4 bb = *reinterpret_cast<const float4*>(bias + c);
                float bj[4] = {bb.x, bb.y, bb.z, bb.w};
                short4v yv = {};
                if (ok) yv = *reinterpret_cast<const short4v*>(y1res + (size_t)r * 128 + c);
                short4v p;
                #pragma unroll
                for (int j = 0; j < 4; ++j) {
                    float o = 0.f;
                    if (ok) {
                        o = acc[m][nn][j] + bj[j]
                          + fmaf(b2f((ushort)yv[j]), s_sh[c + j], t_sh[c + j]);
                    }
                    ps[nn][j] += o; ps2[nn][j] += o * o;
                    p[j] = (short)f2b(o);
                }
                if (ok)
                    *reinterpret_cast<short4v*>((ushort*)C + (size_t)r * 128 + c) = p;
            }
        }
        #pragma unroll
        for (int nn = 0; nn < 4; ++nn)
            #pragma unroll
            for (int j = 0; j < 4; ++j) {
                float a = ps[nn][j], b = ps2[nn][j];
                #pragma unroll
                for (int o2 = 1; o2 < 16; o2 <<= 1) {
                    a += __shfl_xor(a, o2);
                    b += __shfl_xor(b, o2);
                }
                if (rl == 0) {
                    int c = wc + nn * 16 + ch4 + j;
                    atomicAdd(&csum[c], a);
                    atomicAdd(&csum2[c], b);
                }
            }
        __syncthreads();
        if (t < 128) {
            atomicAdd(bn_out + t, csum[t]);
            atomicAdd(bn_out + 128 + t, csum2[t]);
        }
        return;
    }

    // EPI == 0
    #pragma unroll
    for (int m = 0; m < 2; ++m) {
        int r = r0 + wr + m * 16 + rl;
        if (r >= n) continue;
        #pragma unroll
        for (int nn = 0; nn < 4; ++nn) {
            int c = c0 + wc + nn * 16 + ch4;
            f32x4 vacc = acc[m][nn];
            float4 bb = make_float4(0.f, 0.f, 0.f, 0.f);
            if (bias) bb = *reinterpret_cast<const float4*>(bias + c);
            float o0 = vacc[0] + bb.x, o1 = vacc[1] + bb.y;
            float o2 = vacc[2] + bb.z, o3 = vacc[3] + bb.w;
            if (RELU) {
                o0 = fmaxf(o0, 0.f); o1 = fmaxf(o1, 0.f);
                o2 = fmaxf(o2, 0.f); o3 = fmaxf(o3, 0.f);
            }
            short4v p;
            p[0] = (short)f2b(o0); p[1] = (short)f2b(o1);
            p[2] = (short)f2b(o2); p[3] = (short)f2b(o3);
            *reinterpret_cast<short4v*>((ushort*)C + (size_t)r * M + c) = p;
        }
    }
}

// ---------------------------------------------------------------------------
// Fused FFN + LN2 (r16 proven): W1/W2 time-share one 16KB buffer; 64KB LDS.
// ---------------------------------------------------------------------------
__global__ __launch_bounds__(512) void ffn_ln_kernel(
    const ushort* __restrict__ X,   const ushort* __restrict__ W1g,  // 512x128
    const ushort* __restrict__ W2g,                                   // 128x512
    const float* __restrict__ b1v,  const float* __restrict__ b2v,
    const float* __restrict__ lng,  const float* __restrict__ lnb,
    ushort* __restrict__ out, int n)
{
    __shared__ ushort Xs[128 * 128];
    __shared__ ushort FF1[128 * 64];
    __shared__ ushort Wbuf[64 * 128];

    const int t    = threadIdx.x;
    const int lane = t & 63;
    const int w    = t >> 6;
    const int r0   = blockIdx.x * 128;
    const int rl   = lane & 15;
    const int kh   = lane >> 4;
    const int wr   = (w >> 1) * 32;
    const int wc1  = (w & 1) * 32;
    const int wc2  = (w & 1) * 64;

    #pragma unroll
    for (int i = 0; i < 4; ++i) {
        int s = t + i * 512;
        int row = s >> 4, pos = s & 15;
        int srcch = pos ^ ((row >> 1) & 7);
        if (r0 + row < n)
            __builtin_amdgcn_global_load_lds(
                (const __attribute__((address_space(1))) void*)(X + (size_t)(r0 + row) * 128 + srcch * 8),
                (__attribute__((address_space(3))) void*)&Xs[s * 8], 16, 0, 0);
    }
    __syncthreads();

    f32x4 acc2[2][4] = {};

    for (int c = 0; c < 8; ++c) {
        #pragma unroll
        for (int i = 0; i < 2; ++i) {
            int s = t + i * 512;
            int row = s >> 4, pos = s & 15;
            int srcch = pos ^ ((row >> 1) & 7);
            __builtin_amdgcn_global_load_lds(
                (const __attribute__((address_space(1))) void*)(W1g + (size_t)(c * 64 + row) * 128 + srcch * 8),
                (__attribute__((address_space(3))) void*)&Wbuf[s * 8], 16, 0, 0);
        }
        __syncthreads();

        f32x4 acc1[2][2] = {};
        #pragma unroll
        for (int ks = 0; ks < 4; ++ks) {
            int chn = ks * 4 + kh;
            short8 af[2], bf[2];
            #pragma unroll
            for (int m = 0; m < 2; ++m) {
                int row = wr + m * 16 + rl;
                af[m] = *reinterpret_cast<const short8*>(&Xs[row * 128 + (chn ^ ((row >> 1) & 7)) * 8]);
            }
            #pragma unroll
            for (int nn = 0; nn < 2; ++nn) {
                int colL = wc1 + nn * 16 + rl;
                bf[nn] = *reinterpret_cast<const short8*>(&Wbuf[colL * 128 + (chn ^ ((colL >> 1) & 7)) * 8]);
            }
            #pragma unroll
            for (int m = 0; m < 2; ++m)
                #pragma unroll
                for (int nn = 0; nn < 2; ++nn)
                    acc1[m][nn] = __builtin_amdgcn_mfma_f32_16x16x32_bf16(
                        bf[nn], af[m], acc1[m][nn], 0, 0, 0);
        }
        #pragma unroll
        for (int m = 0; m < 2; ++m) {
            int row = wr + m * 16 + rl;
            #pragma unroll
            for (int nn = 0; nn < 2; ++nn) {
                int colL = wc1 + nn * 16 + kh * 4;
                float4 bb = *reinterpret_cast<const float4*>(b1v + c * 64 + colL);
                short4v p;
                p[0] = (short)f2b(fmaxf(acc1[m][nn][0] + bb.x, 0.f));
                p[1] = (short)f2b(fmaxf(acc1[m][nn][1] + bb.y, 0.f));
                p[2] = (short)f2b(fmaxf(acc1[m][nn][2] + bb.z, 0.f));
                p[3] = (short)f2b(fmaxf(acc1[m][nn][3] + bb.w, 0.f));
                int chn = colL >> 3, half = (colL >> 2) & 1;
                *reinterpret_cast<short4v*>(
                    &FF1[row * 64 + (chn ^ ((row >> 1) & 7)) * 8 + half * 4]) = p;
            }
        }
        __syncthreads();

        #pragma unroll
        for (int i = 0; i < 2; ++i) {
            int s = t + i * 512;
            int row = s >> 3, pos = s & 7;
            int srcch = pos ^ ((row >> 1) & 7);
            __builtin_amdgcn_global_load_lds(
                (const __attribute__((address_space(1))) void*)(W2g + (size_t)row * 512 + c * 64 + srcch * 8),
                (__attribute__((address_space(3))) void*)&Wbuf[s * 8], 16, 0, 0);
        }
        __syncthreads();

        #pragma unroll
        for (int ks = 0; ks < 2; ++ks) {
            int chn = ks * 4 + kh;
            short8 af[2], bf[4];
            #pragma unroll
            for (int m = 0; m < 2; ++m) {
                int row = wr + m * 16 + rl;
                af[m] = *reinterpret_cast<const short8*>(&FF1[row * 64 + (chn ^ ((row >> 1) & 7)) * 8]);
            }
            #pragma unroll
            for (int nn = 0; nn < 4; ++nn) {
                int col = wc2 + nn * 16 + rl;
                bf[nn] = *reinterpret_cast<const short8*>(&Wbuf[col * 64 + (chn ^ ((col >> 1) & 7)) * 8]);
            }
            #pragma unroll
            for (int m = 0; m < 2; ++m)
                #pragma unroll
                for (int nn = 0; nn < 4; ++nn)
                    acc2[m][nn] = __builtin_amdgcn_mfma_f32_16x16x32_bf16(
                        bf[nn], af[m], acc2[m][nn], 0, 0, 0);
        }
        __syncthreads();
    }

    float* lnSf  = (float*)FF1;
    float* lnS2f = lnSf + 256;
    const int ch4 = kh * 4;
    #pragma unroll
    for (int m = 0; m < 2; ++m) {
        int rloc = wr + m * 16 + rl;
        float s = 0.f, s2 = 0.f;
        #pragma unroll
        for (int nn = 0; nn < 4; ++nn) {
            int col = wc2 + nn * 16 + ch4;
            int chn = col >> 3;
            short4v xv = *reinterpret_cast<const short4v*>(
                &Xs[rloc * 128 + (chn ^ ((rloc >> 1) & 7)) * 8 + ((col >> 2) & 1) * 4]);
            float4 bb = *reinterpret_cast<const float4*>(b2v + col);
            float bj[4] = {bb.x, bb.y, bb.z, bb.w};
            #pragma unroll
            for (int j = 0; j < 4; ++j) {
                float o = acc2[m][nn][j] + bj[j] + b2f((ushort)xv[j]);
                acc2[m][nn][j] = o;
                s += o; s2 += o * o;
            }
        }
        s  += __shfl_xor(s, 16);  s  += __shfl_xor(s, 32);
        s2 += __shfl_xor(s2, 16); s2 += __shfl_xor(s2, 32);
        if (kh == 0) {
            lnSf[rloc * 2 + (w & 1)]  = s;
            lnS2f[rloc * 2 + (w & 1)] = s2;
        }
    }
    __syncthreads();
    #pragma unroll
    for (int m = 0; m < 2; ++m) {
        int rloc = wr + m * 16 + rl;
        int r = r0 + rloc;
        float S  = lnSf[rloc * 2 + 0] + lnSf[rloc * 2 + 1];
        float S2 = lnS2f[rloc * 2 + 0] + lnS2f[rloc * 2 + 1];
        float mean = S * (1.f / 128.f);
        float var  = S2 * (1.f / 128.f) - mean * mean;
        float rs   = rsqrtf(var + 1e-5f);
        if (r >= n) continue;
        #pragma unroll
        for (int nn = 0; nn < 4; ++nn) {
            int col = wc2 + nn * 16 + ch4;
            float4 gv = *reinterpret_cast<const float4*>(lng + col);
            float4 bv = *reinterpret_cast<const float4*>(lnb + col);
            float gj[4] = {gv.x, gv.y, gv.z, gv.w};
            float bj[4] = {bv.x, bv.y, bv.z, bv.w};
            short4v p;
            #pragma unroll
            for (int j = 0; j < 4; ++j)
                p[j] = (short)f2b((acc2[m][nn][j] - mean) * rs * gj[j] + bj[j]);
            *reinterpret_cast<short4v*>(out + (size_t)r * 128 + col) = p;
        }
    }
}

// ---------------------------------------------------------------------------
__global__ __launch_bounds__(256) void zero_kernel(int4* __restrict__ p, int n4)
{
    int i = blockIdx.x * blockDim.x + threadIdx.x;
    int stride = gridDim.x * blockDim.x;
    int4 z = make_int4(0, 0, 0, 0);
    for (; i < n4; i += stride) p[i] = z;
}

// ---------------------------------------------------------------------------
// Merged histogram + weight prep
// ---------------------------------------------------------------------------
struct WPtrs { const float* p[7]; };

__global__ __launch_bounds__(256) void hist_prep_kernel(
    const int* __restrict__ dst, int* __restrict__ cnt, int E_, int Eb,
    const float* __restrict__ Win, const float* __restrict__ bin_,
    const float* __restrict__ Wout, const float* __restrict__ bout,
    WPtrs wp, ushort* __restrict__ wbf, float* __restrict__ bfused)
{
    int blk = blockIdx.x;
    if (blk < Eb) {
        int e = blk * 256 + threadIdx.x;
        if (e < E_) atomicAdd(cnt + dst[e], 1);
        return;
    }
    int b = blk - Eb;
    if (b < 64) {
        int idx = b * 256 + threadIdx.x;
        int i = idx >> 7, c = idx & 127;
        const float* WinV = Win + 256 * 128;
        float s = 0.f;
        for (int j = 0; j < 128; ++j)
            s = fmaf(Wout[i * 128 + j], WinV[j * 128 + c], s);
        wbf[245760 + idx] = f2b(s);
        if (c == 0) {
            float tb = bout[i];
            for (int j = 0; j < 128; ++j)
                tb = fmaf(Wout[i * 128 + j], bin_[256 + j], tb);
            bfused[i] = tb;
        }
    } else {
        const int off[8] = {0, 65536, 131072, 147456, 163840, 180224, 212992, 245760};
        int e0 = ((b - 64) * 256 + threadIdx.x) * 4;
        if (e0 >= 245760) return;
        int s = 0;
        #pragma unroll
        for (int j = 1; j < 7; ++j) if (e0 >= off[j]) s = j;
        float4 f = *reinterpret_cast<const float4*>(wp.p[s] + (e0 - off[s]));
        short4v o;
        o[0] = (short)f2b(f.x); o[1] = (short)f2b(f.y);
        o[2] = (short)f2b(f.z); o[3] = (short)f2b(f.w);
        *reinterpret_cast<short4v*>(wbf + e0) = o;
    }
}

__global__ __launch_bounds__(256) void scan_block_kernel(
    int* __restrict__ data, int* __restrict__ bsum, int n)
{
    __shared__ int tmp[256];
    int i = blockIdx.x * 256 + threadIdx.x;
    int v = (i < n) ? data[i] : 0;
    tmp[threadIdx.x] = v;
    __syncthreads();
    #pragma unroll
    for (int o = 1; o < 256; o <<= 1) {
        int y = (threadIdx.x >= o) ? tmp[threadIdx.x - o] : 0;
        __syncthreads();
        tmp[threadIdx.x] += y;
        __syncthreads();
    }
    if (i < n) data[i] = tmp[threadIdx.x] - v;
    if (threadIdx.x == 255) bsum[blockIdx.x] = tmp[255];
}

__global__ __launch_bounds__(256) void add_off_kernel(
    int* __restrict__ data, const int* __restrict__ bsum, int n, int nb)
{
    __shared__ int red[4];
    int b = blockIdx.x;
    int v = (threadIdx.x < b && threadIdx.x < nb) ? bsum[threadIdx.x] : 0;
    #pragma unroll
    for (int o = 1; o < 64; o <<= 1) v += __shfl_xor(v, o);
    if ((threadIdx.x & 63) == 0) red[threadIdx.x >> 6] = v;
    __syncthreads();
    int off = red[0] + red[1] + red[2] + red[3];
    int i = b * 256 + threadIdx.x;
    if (i < n) data[i] += off;
}

__global__ void scatter_kernel(const int* __restrict__ src, const int* __restrict__ dst,
                               int* __restrict__ rowptr, int* __restrict__ csr_src, int E_)
{
    int e = blockIdx.x * blockDim.x + threadIdx.x;
    if (e >= E_) return;
    int pos = atomicAdd(rowptr + dst[e], 1);
    csr_src[pos] = src[e];
}

// ---------------------------------------------------------------------------
// Gather attention: 32 lanes/node = 4 edge-slots x 8 heads (r12 proven).
// Writes y1 = hsub + wV/z as bf16.
// ---------------------------------------------------------------------------
__global__ __launch_bounds__(256) void attn_agg_kernel(
    const int* __restrict__ rowptr, const int* __restrict__ csr_src,
    const ushort* __restrict__ QKV, const ushort* __restrict__ hsub,
    ushort* __restrict__ out, int n)
{
    int node  = (blockIdx.x * blockDim.x + threadIdx.x) >> 5;
    int lane5 = threadIdx.x & 31;
    int slot  = lane5 >> 3;   // 0..3
    int hd    = lane5 & 7;    // head; channels [16*hd, 16*hd+16)
    bool valid = node < n;
    int nd = valid ? node : 0;
    int start = (valid && nd) ? rowptr[nd - 1] : 0;
    int end   = valid ? rowptr[nd] : 0;

    const ushort* qp = QKV + (size_t)nd * 384 + hd * 16;
    short8 q0 = *reinterpret_cast<const short8*>(qp);
    short8 q1 = *reinterpret_cast<const short8*>(qp + 8);
    float q[16];
    #pragma unroll
    for (int i = 0; i < 8; ++i) { q[i] = b2f((ushort)q0[i]); q[8 + i] = b2f((ushort)q1[i]); }

    float acc[16] = {};
    float zh = 0.f;
    for (int j = start; j < end; j += 4) {
        int idx = j + slot;
        if (idx < end) {
            int s = csr_src[idx];
            const ushort* kp = QKV + (size_t)s * 384 + 128 + hd * 16;
            short8 k0 = *reinterpret_cast<const short8*>(kp);
            short8 k1 = *reinterpret_cast<const short8*>(kp + 8);
            float p = 0.f;
            #pragma unroll
            for (int i = 0; i < 8; ++i) {
                p = fmaf(b2f((ushort)k0[i]), q[i], p);
                p = fmaf(b2f((ushort)k1[i]), q[8 + i], p);
            }
            float sc = __expf(fminf(fmaxf(p * 0.25f, -5.f), 5.f));
            short8 v0 = *reinterpret_cast<const short8*>(kp + 128);
            short8 v1 = *reinterpret_cast<const short8*>(kp + 136);
            #pragma unroll
            for (int i = 0; i < 8; ++i) {
                acc[i]     = fmaf(sc, b2f((ushort)v0[i]), acc[i]);
                acc[8 + i] = fmaf(sc, b2f((ushort)v1[i]), acc[8 + i]);
            }
            zh += sc;
        }
    }
    #pragma unroll
    for (int i = 0; i < 16; ++i) {
        acc[i] += __shfl_xor(acc[i], 8);
        acc[i] += __shfl_xor(acc[i], 16);
    }
    zh += __shfl_xor(zh, 8);
    zh += __shfl_xor(zh, 16);

    if (slot == 0 && valid) {
        const ushort* hp = hsub + (size_t)nd * D_ + hd * 16;
        short8 h0 = *reinterpret_cast<const short8*>(hp);
        short8 h1 = *reinterpret_cast<const short8*>(hp + 8);
        float inv = 1.f / zh;
        short8 o0, o1;
        #pragma unroll
        for (int i = 0; i < 8; ++i) {
            o0[i] = (short)f2b(b2f((ushort)h0[i]) + acc[i] * inv);
            o1[i] = (short)f2b(b2f((ushort)h1[i]) + acc[8 + i] * inv);
        }
        ushort* op = out + (size_t)nd * D_ + hd * 16;
        *reinterpret_cast<short8*>(op)     = o0;
        *reinterpret_cast<short8*>(op + 8) = o1;
    }
}

// ---------------------------------------------------------------------------
// BN stats over bf16 input: sums[c], sums[128+c].
// ---------------------------------------------------------------------------
__global__ __launch_bounds__(256) void bn_stats_kernel(
    const ushort* __restrict__ x, float* __restrict__ sums, int n)
{
    int c    = threadIdx.x & 127;
    int half = threadIdx.x >> 7;
    float s = 0.f, s2 = 0.f;
    for (int r = blockIdx.x * 2 + half; r < n; r += gridDim.x * 2) {
        float v = b2f(x[(size_t)r * D_ + c]);
        s += v; s2 += v * v;
    }
    __shared__ float ls[256], ls2[256];
    ls[threadIdx.x] = s; ls2[threadIdx.x] = s2;
    __syncthreads();
    if (half == 0) {
        s  += ls[threadIdx.x + 128];
        s2 += ls2[threadIdx.x + 128];
        atomicAdd(sums + c, s);
        atomicAdd(sums + 128 + c, s2);
    }
}

// final BN: bf16 in -> f32 out, 4 elems/thread
__global__ void bn_norm_kernel(const ushort* __restrict__ x,
                               const float* __restrict__ stats,
                               const float* __restrict__ g, const float* __restrict__ b,
                               float* __restrict__ out, float invn, int total4)
{
    int i = blockIdx.x * blockDim.x + threadIdx.x;
    if (i >= total4) return;
    int cb = (i << 2) & 127;
    short4v v = reinterpret_cast<const short4v*>(x)[i];
    float r[4];
    #pragma unroll
    for (int q = 0; q < 4; ++q) {
        int c = cb + q;
        float m   = stats[c] * invn;
        float var = stats[128 + c] * invn - m * m;
        float rs  = rsqrtf(var + 1e-5f);
        r[q] = (b2f((ushort)v[q]) - m) * rs * g[c] + b[c];
    }
    float4 o; o.x = r[0]; o.y = r[1]; o.z = r[2]; o.w = r[3];
    reinterpret_cast<float4*>(out)[i] = o;
}

// ---------------------------------------------------------------------------
extern "C" void kernel_launch(void* const* d_in, const int* in_sizes, int n_in,
                              void* d_out, int out_size, void* d_ws, size_t ws_size,
                              hipStream_t stream)
{
    const float* h    = (const float*)d_in[0];
    const int*   src  = (const int*)d_in[1];
    const int*   dst  = (const int*)d_in[2];
    const float* Win  = (const float*)d_in[3];
    const float* bin_ = (const float*)d_in[4];
    const float* Wout = (const float*)d_in[5];
    const float* bout = (const float*)d_in[6];
    const float* Wte1 = (const float*)d_in[7];
    const float* bte1 = (const float*)d_in[8];
    const float* Wte2 = (const float*)d_in[9];
    const float* bte2 = (const float*)d_in[10];
    const float* ln1g = (const float*)d_in[11];
    const float* ln1b = (const float*)d_in[12];
    const float* ln2g = (const float*)d_in[13];
    const float* ln2b = (const float*)d_in[14];
    const float* WQ   = (const float*)d_in[15];
    const float* WK   = (const float*)d_in[16];
    const float* WV   = (const float*)d_in[17];
    const float* W1   = (const float*)d_in[18];
    const float* b1   = (const float*)d_in[19];
    const float* W2   = (const float*)d_in[20];
    const float* b2   = (const float*)d_in[21];
    const float* bn1g = (const float*)d_in[22];
    const float* bn1b = (const float*)d_in[23];
    const float* bn2g = (const float*)d_in[24];
    const float* bn2b = (const float*)d_in[25];

    const int N_ = in_sizes[0] / D_;
    const int E_ = in_sizes[1];
    const size_t S2 = (size_t)N_ * D_ / 2;   // float units of one NxD bf16 buffer

    float* ws = (float*)d_ws;
    // layout (float units): A,B,C bf16 NxD; D bf16 Nx512; tail at 7S2
    size_t off_tail = 7 * S2;
    size_t need = (off_tail + 131072 + 128 + 512) * sizeof(float)
                + (size_t)(N_ + E_ + 256) * sizeof(int) + 4096;
    if (ws_size < need) return;

    ushort* bufA   = (ushort*)ws;                 // x -> y1 (bf16)
    ushort* bufB   = (ushort*)(ws + S2);          // y2 (bf16)
    ushort* bufC   = (ushort*)(ws + 2 * S2);      // hsub (bf16)
    ushort* bufD   = (ushort*)(ws + 3 * S2);      // QKV / f1 (bf16 Nx512 max)
    ushort* wbf    = (ushort*)(ws + off_tail);
    float*  bfused = ws + off_tail + 131072;
    float*  stats  = bfused + 128;
    int* rowptr  = (int*)(stats + 512);
    int* csr_src = rowptr + N_;
    int* bsum    = csr_src + E_;

    const ushort* Wte1_bf = wbf;
    const ushort* Wte2_bf = wbf + 65536;
    const ushort* WQKV_bf = wbf + 131072;
    const ushort* W1_bf   = wbf + 180224;
    const ushort* W2_bf   = wbf + 212992;
    ushort*       Wf_bf   = wbf + 245760;

    dim3 blk(256);
    dim3 blk512(512);
    const int rowBlocks = (N_ + 127) / 128;
    const int totElems  = N_ * D_;
    const dim3 gNode((N_ + 7) / 8);               // 8 nodes/block (32 lanes/node)
    const int nb = (N_ + 255) / 256;
    const int Eb = (E_ + 255) / 256;
    const float invn = 1.f / (float)N_;

    {
        int n4 = (512 + N_) / 4;
        int zblocks = (n4 + 255) / 256;
        if (zblocks > 128) zblocks = 128;
        zero_kernel<<<dim3(zblocks), blk, 0, stream>>>((int4*)stats, n4);
    }

    // --- CSR build + weight prep (merged) ---
    WPtrs wp;
    wp.p[0] = Wte1; wp.p[1] = Wte2; wp.p[2] = WQ; wp.p[3] = WK; wp.p[4] = WV;
    wp.p[5] = W1;   wp.p[6] = W2;
    hist_prep_kernel<<<dim3(Eb + 304), blk, 0, stream>>>(
        dst, rowptr, E_, Eb, Win, bin_, Wout, bout, wp, wbf, bfused);
    scan_block_kernel<<<dim3(nb), blk, 0, stream>>>(rowptr, bsum, N_);
    add_off_kernel<<<dim3(nb), blk, 0, stream>>>(rowptr, bsum, N_, nb);
    scatter_kernel<<<dim3(Eb), blk, 0, stream>>>(src, dst, rowptr, csr_src, E_);

    // --- per-node TransformerEncoder ---
    gemm_bf16<1, 1, false, true><<<dim3(rowBlocks, 1), blk512, 0, stream>>>(
        h, Wf_bf, bfused, bufA, nullptr, nullptr, nullptr, nullptr,
        h, nullptr, ln1g, ln1b, 0.f, N_, 128, 128);
    ffn_ln_kernel<<<dim3(rowBlocks), blk512, 0, stream>>>(
        bufA, Wte1_bf, Wte2_bf, bte1, bte2, ln2g, ln2b, bufC, N_);

    // --- graph multi-head attention ---
    gemm_bf16<0, 0, false, false><<<dim3(rowBlocks, 3), blk512, 0, stream>>>(
        bufC, WQKV_bf, nullptr, bufD, nullptr, nullptr, nullptr, nullptr,
        nullptr, nullptr, nullptr, nullptr, 0.f, N_, 128, 384);
    attn_agg_kernel<<<gNode, blk, 0, stream>>>(
        rowptr, csr_src, bufD, bufC, bufA, N_);                          // y1 (bf16)

    // --- BN1 stats ---
    bn_stats_kernel<<<dim3(512), blk, 0, stream>>>(bufA, stats, N_);

    // --- FFN + BN2 ---
    gemm_bf16<2, 0, true, false><<<dim3(rowBlocks, 2), blk512, 0, stream>>>(
        bufA, W1_bf, b1, bufD, stats, nullptr, bn1g, bn1b,
        nullptr, nullptr, nullptr, nullptr, invn, N_, 128, 256);
    gemm_bf16<0, 2, false, false><<<dim3(rowBlocks, 1), blk512, 0, stream>>>(
        bufD, W2_bf, b2, bufB, stats, stats + 256, bn1g, bn1b,
        nullptr, bufA, nullptr, nullptr, invn, N_, 256, 128);
    bn_norm_kernel<<<dim3((totElems / 4 + 255) / 256), blk, 0, stream>>>(
        bufB, stats + 256, bn2g, bn2b, (float*)d_out, invn, totElems / 4);
}